// Round 19
// baseline (140.333 us; speedup 1.0000x reference)
//
#include <hip/hip_runtime.h>

#define N_NODES 40000
#define E_EDGES 640000
#define E_TOT   (E_EDGES + N_NODES)
#define SCAN_BLOCKS ((N_NODES + 255) / 256)   // 157
#define G1_BLOCKS 625                         // 64 rows per block (4 waves x 16)
#define HIST_BLOCKS ((E_EDGES + 255) / 256)   // 2500

typedef unsigned int uint;
typedef unsigned short ushort;
typedef __attribute__((ext_vector_type(8))) short short8v;   // 8 bf16 (4 VGPRs)
typedef __attribute__((ext_vector_type(4))) float f32x4;     // MFMA accumulator

// bf16 helpers (RNE pack, cheap unpack)
__device__ __forceinline__ ushort f2bf(float f) {
    uint u = __float_as_uint(f);
    u += 0x7FFFu + ((u >> 16) & 1u);
    return (ushort)(u >> 16);
}
__device__ __forceinline__ uint pk_bf(float lo, float hi) {
    return (uint)f2bf(lo) | ((uint)f2bf(hi) << 16);
}
__device__ __forceinline__ float bf_lo(uint w) { return __uint_as_float(w << 16); }
__device__ __forceinline__ float bf_hi(uint w) { return __uint_as_float(w & 0xFFFF0000u); }

// ===========================================================================
// prep: blocks 0..39  -> cnt[i] = 1 (self-loop baked in -> occupies rank 0)
//       blocks 40..47 -> pack W1 into MFMA B-fragment order; zero scan flag
// ===========================================================================
__global__ __launch_bounds__(256) void prep_kernel(
    const float* __restrict__ W1, int4* __restrict__ cnt4, ushort* __restrict__ Wf,
    int* __restrict__ done)
{
    if (blockIdx.x == 0 && threadIdx.x == 0) *done = 0;
    if (blockIdx.x < 40) {
        const int i = blockIdx.x * 256 + threadIdx.x;
        if (i < 40064 / 4) cnt4[i] = make_int4(1, 1, 1, 1);
        return;
    }
    const int s = (blockIdx.x - 40) * 256 + threadIdx.x;   // 0..2047
    if (s >= 2048) return;
    const int kk = s >> 9;          // K-step (32 per step)
    const int rem = s & 511;
    const int ct = rem >> 6;        // column tile (16 cols)
    const int l = rem & 63;         // lane
    const int k0 = kk * 32 + (l >> 4) * 8;
    const int col = ct * 16 + (l & 15);
    uint4 o;
    o.x = pk_bf(W1[(k0 + 0) * 128 + col], W1[(k0 + 1) * 128 + col]);
    o.y = pk_bf(W1[(k0 + 2) * 128 + col], W1[(k0 + 3) * 128 + col]);
    o.z = pk_bf(W1[(k0 + 4) * 128 + col], W1[(k0 + 5) * 128 + col]);
    o.w = pk_bf(W1[(k0 + 6) * 128 + col], W1[(k0 + 7) * 128 + col]);
    ((uint4*)Wf)[s] = o;
}

// ===========================================================================
// FUSED gemm1 (MFMA) ∥ hist+rank (block-range partition, independent):
//   blocks [0, G1_BLOCKS)            -> MFMA GEMM tile (needs only x, Wf)
//   blocks [G1_BLOCKS, +HIST_BLOCKS) -> histogram; rank[e] = old count
// ===========================================================================
__global__ __launch_bounds__(256) void gemm1_hist_kernel(
    const float* __restrict__ x, const ushort* __restrict__ Wf,
    const float* __restrict__ a_src, const float* __restrict__ a_dst,
    ushort* __restrict__ h1b, float* __restrict__ asrc, float* __restrict__ adst,
    const int* __restrict__ eidx, int* __restrict__ cnt, int* __restrict__ rank)
{
    if (blockIdx.x >= G1_BLOCKS) {
        const int e = (blockIdx.x - G1_BLOCKS) * 256 + threadIdx.x;
        if (e < E_EDGES)
            rank[e] = atomicAdd(&cnt[eidx[E_EDGES + e]], 1);
        return;
    }

    // ---- gemm1 partition: one wave = 16 rows x 128 cols, K-loop 4 x 32 ----
    const int wv = threadIdx.x >> 6;
    const int lane = threadIdx.x & 63;
    const int rowbase = blockIdx.x * 64 + wv * 16;
    const int arow = rowbase + (lane & 15);
    const int kof = (lane >> 4) * 8;

    f32x4 acc0 = {0.f,0.f,0.f,0.f}, acc1 = {0.f,0.f,0.f,0.f};
    f32x4 acc2 = {0.f,0.f,0.f,0.f}, acc3 = {0.f,0.f,0.f,0.f};
    f32x4 acc4 = {0.f,0.f,0.f,0.f}, acc5 = {0.f,0.f,0.f,0.f};
    f32x4 acc6 = {0.f,0.f,0.f,0.f}, acc7 = {0.f,0.f,0.f,0.f};

    const short8v* WfV = (const short8v*)Wf;
#pragma unroll
    for (int kk = 0; kk < 4; ++kk) {
        const float* ap = &x[(size_t)arow * 128 + kk * 32 + kof];
        const float4 a0 = *(const float4*)ap;
        const float4 a1 = *(const float4*)(ap + 4);
        short8v af;
        af[0] = (short)f2bf(a0.x); af[1] = (short)f2bf(a0.y);
        af[2] = (short)f2bf(a0.z); af[3] = (short)f2bf(a0.w);
        af[4] = (short)f2bf(a1.x); af[5] = (short)f2bf(a1.y);
        af[6] = (short)f2bf(a1.z); af[7] = (short)f2bf(a1.w);
        const int base = kk * 8 * 64 + lane;
        acc0 = __builtin_amdgcn_mfma_f32_16x16x32_bf16(af, WfV[base + 0 * 64], acc0, 0, 0, 0);
        acc1 = __builtin_amdgcn_mfma_f32_16x16x32_bf16(af, WfV[base + 1 * 64], acc1, 0, 0, 0);
        acc2 = __builtin_amdgcn_mfma_f32_16x16x32_bf16(af, WfV[base + 2 * 64], acc2, 0, 0, 0);
        acc3 = __builtin_amdgcn_mfma_f32_16x16x32_bf16(af, WfV[base + 3 * 64], acc3, 0, 0, 0);
        acc4 = __builtin_amdgcn_mfma_f32_16x16x32_bf16(af, WfV[base + 4 * 64], acc4, 0, 0, 0);
        acc5 = __builtin_amdgcn_mfma_f32_16x16x32_bf16(af, WfV[base + 5 * 64], acc5, 0, 0, 0);
        acc6 = __builtin_amdgcn_mfma_f32_16x16x32_bf16(af, WfV[base + 6 * 64], acc6, 0, 0, 0);
        acc7 = __builtin_amdgcn_mfma_f32_16x16x32_bf16(af, WfV[base + 7 * 64], acc7, 0, 0, 0);
    }

    const int cl = lane & 15;   // col within tile
    const int rg = lane >> 4;   // row group
    float csA[8], cdA[8];
#pragma unroll
    for (int ct = 0; ct < 8; ++ct) {
        csA[ct] = a_src[(ct >> 1) * 32 + (ct & 1) * 16 + cl];
        cdA[ct] = a_dst[(ct >> 1) * 32 + (ct & 1) * 16 + cl];
    }
    const f32x4 accv[8] = { acc0, acc1, acc2, acc3, acc4, acc5, acc6, acc7 };
#pragma unroll
    for (int r = 0; r < 4; ++r) {
        const int n = rowbase + rg * 4 + r;
        ushort* hrow = &h1b[(size_t)n * 128 + cl];
#pragma unroll
        for (int ct = 0; ct < 8; ++ct) hrow[ct * 16] = f2bf(accv[ct][r]);
#pragma unroll
        for (int h = 0; h < 4; ++h) {
            float ps = accv[2 * h][r] * csA[2 * h] + accv[2 * h + 1][r] * csA[2 * h + 1];
            float pd = accv[2 * h][r] * cdA[2 * h] + accv[2 * h + 1][r] * cdA[2 * h + 1];
            ps += __shfl_xor(ps, 1); ps += __shfl_xor(ps, 2);
            ps += __shfl_xor(ps, 4); ps += __shfl_xor(ps, 8);
            pd += __shfl_xor(pd, 1); pd += __shfl_xor(pd, 2);
            pd += __shfl_xor(pd, 4); pd += __shfl_xor(pd, 8);
            if (cl == 0) { asrc[n * 4 + h] = ps; adst[n * 4 + h] = pd; }
        }
    }
}

// ===========================================================================
// scanAB: block-local exclusive scan; last block to finish also scans the
// 157 block sums in place (threadfence + atomic counter; bsum read back via
// atomicAdd(p,0) for cross-XCD coherence).
// ===========================================================================
__global__ __launch_bounds__(256) void scanAB_kernel(
    const int* __restrict__ cnt, int* __restrict__ rowptr, int* __restrict__ bsum,
    int* __restrict__ done)
{
    const int i = blockIdx.x * 256 + threadIdx.x;
    const int lane = threadIdx.x & 63;
    const int wave = threadIdx.x >> 6;
    const int v = (i < N_NODES) ? cnt[i] : 0;
    int incl = v;
#pragma unroll
    for (int off = 1; off < 64; off <<= 1) {
        int u = __shfl_up(incl, off);
        if (lane >= off) incl += u;
    }
    __shared__ int ws[4];
    __shared__ int isLast;
    if (lane == 63) ws[wave] = incl;
    __syncthreads();
    int woff = 0;
    if (wave > 0) woff += ws[0];
    if (wave > 1) woff += ws[1];
    if (wave > 2) woff += ws[2];
    if (i <= N_NODES) rowptr[i] = woff + incl - v;   // block-local exclusive
    if (threadIdx.x == 255) bsum[blockIdx.x] = woff + incl;

    __threadfence();
    if (threadIdx.x == 0) isLast = (atomicAdd(done, 1) == SCAN_BLOCKS - 1);
    __syncthreads();
    if (!isLast) return;

    // ---- final scan of bsum[0..SCAN_BLOCKS) by the last block ----
    const int t = threadIdx.x;
    int v2 = 0;
    if (t < SCAN_BLOCKS) v2 = atomicAdd(&bsum[t], 0);   // coherent read
    int incl2 = v2;
#pragma unroll
    for (int off = 1; off < 64; off <<= 1) {
        int u = __shfl_up(incl2, off);
        if (lane >= off) incl2 += u;
    }
    __syncthreads();
    if (lane == 63) ws[wave] = incl2;
    __syncthreads();
    int woff2 = 0;
    if (wave > 0) woff2 += ws[0];
    if (wave > 1) woff2 += ws[1];
    if (wave > 2) woff2 += ws[2];
    if (t < SCAN_BLOCKS) bsum[t] = woff2 + incl2 - v2;  // exclusive
}

// ===========================================================================
// fill (ATOMIC-FREE): esrc[rowptr[d] + bsum[d>>8] + rank[e]] = s.
// ===========================================================================
__global__ __launch_bounds__(256) void fill_kernel(
    const int* __restrict__ eidx, const int* __restrict__ rowptr,
    const int* __restrict__ bsum, const int* __restrict__ rank,
    int* __restrict__ esrc)
{
    const int e = blockIdx.x * 256 + threadIdx.x;
    if (e >= E_TOT) return;
    int s, d, r;
    if (e < E_EDGES) { s = eidx[e]; d = eidx[E_EDGES + e]; r = rank[e]; }
    else             { s = d = e - E_EDGES; r = 0; }
    esrc[rowptr[d] + bsum[d >> 8] + r] = s;
}

// ===========================================================================
// Gather pass 1: 16 lanes per dst node (4 nodes/wave, 32 rows in flight).
// Lane covers 8 bf16 channels (uint4 16B load); fused norm + bias + ELU.
// ===========================================================================
__global__ __launch_bounds__(256) void gather1_kernel(
    const int* __restrict__ rowptr, const int* __restrict__ bsum,
    const int* __restrict__ esrc, const float* __restrict__ asrc,
    const float* __restrict__ adst,
    const ushort* __restrict__ h1b, const float* __restrict__ b,
    float* __restrict__ agg)
{
    const int t = blockIdx.x * 256 + threadIdx.x;
    const int node = t >> 4;                 // grid exact: 2500*256/16 = 40000
    const int l16 = t & 15;
    const int head = l16 >> 2;               // 4 lanes per head
    const int cb = l16 * 8;                  // first of 8 bf16 channels
    const float ad = adst[node * 4 + head];
    const int beg = rowptr[node] + bsum[node >> 8];
    const int end = rowptr[node + 1] + bsum[(node + 1) >> 8];
    float acc0 = 0.f, acc1 = 0.f, acc2 = 0.f, acc3 = 0.f;
    float acc4 = 0.f, acc5 = 0.f, acc6 = 0.f, acc7 = 0.f, den = 0.f;

    int i = beg;
    for (; i + 8 <= end; i += 8) {
        int s[8];
        float a[8];
        uint4 w[8];
#pragma unroll
        for (int j = 0; j < 8; ++j) s[j] = esrc[i + j];
#pragma unroll
        for (int j = 0; j < 8; ++j) a[j] = asrc[s[j] * 4 + head];
#pragma unroll
        for (int j = 0; j < 8; ++j)
            w[j] = *(const uint4*)&h1b[(size_t)s[j] * 128 + cb];
#pragma unroll
        for (int j = 0; j < 8; ++j) {
            float v = a[j] + ad; v = v > 0.f ? v : 0.2f * v;
            const float e = __expf(v);
            den += e;
            acc0 = fmaf(e, bf_lo(w[j].x), acc0);
            acc1 = fmaf(e, bf_hi(w[j].x), acc1);
            acc2 = fmaf(e, bf_lo(w[j].y), acc2);
            acc3 = fmaf(e, bf_hi(w[j].y), acc3);
            acc4 = fmaf(e, bf_lo(w[j].z), acc4);
            acc5 = fmaf(e, bf_hi(w[j].z), acc5);
            acc6 = fmaf(e, bf_lo(w[j].w), acc6);
            acc7 = fmaf(e, bf_hi(w[j].w), acc7);
        }
    }
    for (; i < end; ++i) {
        const int s = esrc[i];
        float av = asrc[s * 4 + head] + ad;
        av = av > 0.f ? av : 0.2f * av;
        const float ex = __expf(av);
        const uint4 w = *(const uint4*)&h1b[(size_t)s * 128 + cb];
        den += ex;
        acc0 = fmaf(ex, bf_lo(w.x), acc0);
        acc1 = fmaf(ex, bf_hi(w.x), acc1);
        acc2 = fmaf(ex, bf_lo(w.y), acc2);
        acc3 = fmaf(ex, bf_hi(w.y), acc3);
        acc4 = fmaf(ex, bf_lo(w.z), acc4);
        acc5 = fmaf(ex, bf_hi(w.z), acc5);
        acc6 = fmaf(ex, bf_lo(w.w), acc6);
        acc7 = fmaf(ex, bf_hi(w.w), acc7);
    }

    const float inv = 1.f / (den + 1e-16f);
    const float4 b0 = *(const float4*)&b[cb];
    const float4 b1 = *(const float4*)&b[cb + 4];
    float o0 = acc0 * inv + b0.x, o1 = acc1 * inv + b0.y;
    float o2 = acc2 * inv + b0.z, o3 = acc3 * inv + b0.w;
    float o4 = acc4 * inv + b1.x, o5 = acc5 * inv + b1.y;
    float o6 = acc6 * inv + b1.z, o7 = acc7 * inv + b1.w;
    o0 = o0 > 0.f ? o0 : expm1f(o0);
    o1 = o1 > 0.f ? o1 : expm1f(o1);
    o2 = o2 > 0.f ? o2 : expm1f(o2);
    o3 = o3 > 0.f ? o3 : expm1f(o3);
    o4 = o4 > 0.f ? o4 : expm1f(o4);
    o5 = o5 > 0.f ? o5 : expm1f(o5);
    o6 = o6 > 0.f ? o6 : expm1f(o6);
    o7 = o7 > 0.f ? o7 : expm1f(o7);
    *(float4*)&agg[(size_t)node * 128 + cb]     = make_float4(o0, o1, o2, o3);
    *(float4*)&agg[(size_t)node * 128 + cb + 4] = make_float4(o4, o5, o6, o7);
}

// ===========================================================================
// GEMM2: h2 = hin @ W2 [40000x128 @ 128x32]; h2 stored bf16 (halves gather2
// traffic, 2.6 MB -> L2-resident); fused attention coeffs (1 head).
// ===========================================================================
__global__ __launch_bounds__(256) void gemm2_kernel(
    const float* __restrict__ hin, const float* __restrict__ W,
    const float* __restrict__ a_src, const float* __restrict__ a_dst,
    ushort* __restrict__ h2b, float* __restrict__ asrc, float* __restrict__ adst)
{
    __shared__ float Ws[128 * 32];   // 16 KB
    {
        const float4* Wg = (const float4*)W;
        float4* Wl = (float4*)Ws;
        for (int i = threadIdx.x; i < 128 * 32 / 4; i += 256) Wl[i] = Wg[i];
    }
    __syncthreads();
    const int row0 = blockIdx.x * 64;
    const int tx = threadIdx.x & 7;
    const int ty = threadIdx.x >> 3;

    float acc[2][4];
#pragma unroll
    for (int r = 0; r < 2; ++r)
#pragma unroll
        for (int c = 0; c < 4; ++c) acc[r][c] = 0.f;

    for (int k0 = 0; k0 < 128; k0 += 4) {
        float xv[2][4];
#pragma unroll
        for (int r = 0; r < 2; ++r) {
            float4 t = *(const float4*)&hin[(size_t)(row0 + ty * 2 + r) * 128 + k0];
            xv[r][0] = t.x; xv[r][1] = t.y; xv[r][2] = t.z; xv[r][3] = t.w;
        }
#pragma unroll
        for (int kk = 0; kk < 4; ++kk) {
            float4 w = *(const float4*)&Ws[(k0 + kk) * 32 + tx * 4];
            float wreg[4] = { w.x, w.y, w.z, w.w };
#pragma unroll
            for (int r = 0; r < 2; ++r)
#pragma unroll
                for (int c = 0; c < 4; ++c)
                    acc[r][c] = fmaf(xv[r][kk], wreg[c], acc[r][c]);
        }
    }

    float as[4], ad[4];
#pragma unroll
    for (int c = 0; c < 4; ++c) {
        as[c] = a_src[tx * 4 + c];
        ad[c] = a_dst[tx * 4 + c];
    }
#pragma unroll
    for (int r = 0; r < 2; ++r) {
        const int n = row0 + ty * 2 + r;
        uint2 o;
        o.x = pk_bf(acc[r][0], acc[r][1]);
        o.y = pk_bf(acc[r][2], acc[r][3]);
        *(uint2*)&h2b[(size_t)n * 32 + tx * 4] = o;
        float ps = 0.f, pd = 0.f;
#pragma unroll
        for (int c = 0; c < 4; ++c) {
            ps = fmaf(acc[r][c], as[c], ps);
            pd = fmaf(acc[r][c], ad[c], pd);
        }
        ps += __shfl_xor(ps, 1); ps += __shfl_xor(ps, 2); ps += __shfl_xor(ps, 4);
        pd += __shfl_xor(pd, 1); pd += __shfl_xor(pd, 2); pd += __shfl_xor(pd, 4);
        if ((threadIdx.x & 7) == 0) { asrc[n] = ps; adst[n] = pd; }
    }
}

// ===========================================================================
// Gather pass 2: 16 lanes per dst node (4 nodes/wave); bf16 h2 rows (64 B);
// 8-deep pipeline; fused norm + bias + ELU.
// ===========================================================================
__global__ __launch_bounds__(256) void gather2_kernel(
    const int* __restrict__ rowptr, const int* __restrict__ bsum,
    const int* __restrict__ esrc,
    const float* __restrict__ asrc, const float* __restrict__ adst,
    const ushort* __restrict__ h2b, const float* __restrict__ b,
    float* __restrict__ agg)
{
    const int t = blockIdx.x * 256 + threadIdx.x;
    const int node = t >> 4;                 // grid exact: 2500*256/16 = 40000
    const int c2 = (t & 15) * 2;             // 2 channels per lane
    const float ad = adst[node];
    const int beg = rowptr[node] + bsum[node >> 8];
    const int end = rowptr[node + 1] + bsum[(node + 1) >> 8];
    float acc0 = 0.f, acc1 = 0.f, den = 0.f;

    int i = beg;
    for (; i + 8 <= end; i += 8) {
        int s[8];
        float a[8];
        uint w[8];
#pragma unroll
        for (int j = 0; j < 8; ++j) s[j] = esrc[i + j];
#pragma unroll
        for (int j = 0; j < 8; ++j) a[j] = asrc[s[j]];
#pragma unroll
        for (int j = 0; j < 8; ++j)
            w[j] = *(const uint*)&h2b[(size_t)s[j] * 32 + c2];
#pragma unroll
        for (int j = 0; j < 8; ++j) {
            float v = a[j] + ad; v = v > 0.f ? v : 0.2f * v;
            const float e = __expf(v);
            den += e;
            acc0 = fmaf(e, bf_lo(w[j]), acc0);
            acc1 = fmaf(e, bf_hi(w[j]), acc1);
        }
    }
    for (; i < end; ++i) {
        const int s = esrc[i];
        float av = asrc[s] + ad;
        av = av > 0.f ? av : 0.2f * av;
        const float ex = __expf(av);
        const uint w = *(const uint*)&h2b[(size_t)s * 32 + c2];
        den += ex;
        acc0 = fmaf(ex, bf_lo(w), acc0);
        acc1 = fmaf(ex, bf_hi(w), acc1);
    }

    const float inv = 1.f / (den + 1e-16f);
    const float2 bv = *(const float2*)&b[c2];
    float o0 = acc0 * inv + bv.x;
    float o1 = acc1 * inv + bv.y;
    o0 = o0 > 0.f ? o0 : expm1f(o0);
    o1 = o1 > 0.f ? o1 : expm1f(o1);
    *(float2*)&agg[(size_t)node * 32 + c2] = make_float2(o0, o1);
}

// ===========================================================================
// Output GEMM: out = h3 @ W_out + b_out  [40000x32 @ 32x112]
// ===========================================================================
__global__ __launch_bounds__(256) void out_gemm_kernel(
    const float* __restrict__ h3, const float* __restrict__ W,
    const float* __restrict__ b, float* __restrict__ out)
{
    __shared__ float Ws[32 * 112];   // 14 KB
    {
        const float4* Wg = (const float4*)W;
        float4* Wl = (float4*)Ws;
        for (int i = threadIdx.x; i < 32 * 112 / 4; i += 256) Wl[i] = Wg[i];
    }
    __syncthreads();
    const int row0 = blockIdx.x * 32;
    const int tc = threadIdx.x & 15;
    const int tr = threadIdx.x >> 4;

    float acc[2][7];
#pragma unroll
    for (int r = 0; r < 2; ++r)
#pragma unroll
        for (int c = 0; c < 7; ++c) acc[r][c] = 0.f;

    for (int k0 = 0; k0 < 32; k0 += 4) {
        float xv[2][4];
#pragma unroll
        for (int r = 0; r < 2; ++r) {
            float4 t = *(const float4*)&h3[(size_t)(row0 + tr * 2 + r) * 32 + k0];
            xv[r][0] = t.x; xv[r][1] = t.y; xv[r][2] = t.z; xv[r][3] = t.w;
        }
#pragma unroll
        for (int kk = 0; kk < 4; ++kk) {
            float wv[7];
#pragma unroll
            for (int c = 0; c < 7; ++c) wv[c] = Ws[(k0 + kk) * 112 + tc * 7 + c];
#pragma unroll
            for (int r = 0; r < 2; ++r)
#pragma unroll
                for (int c = 0; c < 7; ++c)
                    acc[r][c] = fmaf(xv[r][kk], wv[c], acc[r][c]);
        }
    }
#pragma unroll
    for (int r = 0; r < 2; ++r) {
        const int n = row0 + tr * 2 + r;
#pragma unroll
        for (int c = 0; c < 7; ++c)
            out[(size_t)n * 112 + tc * 7 + c] = acc[r][c] + b[tc * 7 + c];
    }
}

// ===========================================================================
extern "C" void kernel_launch(void* const* d_in, const int* in_sizes, int n_in,
                              void* d_out, int out_size, void* d_ws, size_t ws_size,
                              hipStream_t stream) {
    const float* x      = (const float*)d_in[0];
    const int*   eidx   = (const int*)d_in[1];
    const float* W1     = (const float*)d_in[2];
    const float* a_src1 = (const float*)d_in[3];
    const float* a_dst1 = (const float*)d_in[4];
    const float* b1     = (const float*)d_in[5];
    const float* W2     = (const float*)d_in[6];
    const float* a_src2 = (const float*)d_in[7];
    const float* a_dst2 = (const float*)d_in[8];
    const float* b2     = (const float*)d_in[9];
    const float* W_out  = (const float*)d_in[10];
    const float* b_out  = (const float*)d_in[11];
    float* out = (float*)d_out;

    // ---- workspace layout (~38 MB) ----
    int* rowptr = (int*)d_ws;                 // 40064 (uses [0..40000])
    int* cnt    = rowptr + 40064;             // 40064 histogram (init = 1)
    int* bsum   = cnt + 40064;                // 192 block sums
    int* done   = bsum + 192;                 // 16 (scanAB completion counter)
    int* rank   = done + 16;                  // 680000 per-edge bucket rank
    ushort* Wf  = (ushort*)(rank + 680000);   // 16384 bf16 (frag-ordered W1)
    int* esrc   = (int*)(Wf + 16384);         // 680000 CSR edge sources
    ushort* h1b  = (ushort*)(esrc + 680000);  // 40000*128 bf16
    float* asrc1 = (float*)(h1b + 5120000);   // 40000*4
    float* adst1 = asrc1 + 160000;            // 40000*4
    float* agg1  = adst1 + 160000;            // 40000*128
    // after gather1, h1b region is dead -> layer-2 buffers overlay it
    ushort* h2b  = (ushort*)h1b;              // 40000*32 bf16
    float* asrc2 = (float*)(h2b + 1280000);   // 40000
    float* adst2 = asrc2 + 40000;             // 40000
    float* agg2  = adst2 + 40000;             // 40000*32

    // cnt=1 init + W1 fragment pack + scan-flag zero
    prep_kernel<<<48, 256, 0, stream>>>(W1, (int4*)cnt, Wf, done);

    // Layer-1 GEMM (MFMA) ∥ histogram-with-rank
    gemm1_hist_kernel<<<G1_BLOCKS + HIST_BLOCKS, 256, 0, stream>>>(
        x, Wf, a_src1, a_dst1, h1b, asrc1, adst1, eidx, cnt, rank);

    // CSR scan (fused A+B via last-block finalize)
    scanAB_kernel<<<SCAN_BLOCKS, 256, 0, stream>>>(cnt, rowptr, bsum, done);

    // Atomic-free bucket fill
    fill_kernel<<<(E_TOT + 255) / 256, 256, 0, stream>>>(
        eidx, rowptr, bsum, rank, esrc);

    // Layer 1 aggregate (4 nodes/wave, 32 rows in flight)
    gather1_kernel<<<2500, 256, 0, stream>>>(rowptr, bsum, esrc, asrc1, adst1,
                                             h1b, b1, agg1);

    // Layer 2
    gemm2_kernel<<<625, 256, 0, stream>>>(agg1, W2, a_src2, a_dst2, h2b, asrc2, adst2);
    gather2_kernel<<<2500, 256, 0, stream>>>(rowptr, bsum, esrc, asrc2, adst2,
                                             h2b, b2, agg2);

    // Output projection
    out_gemm_kernel<<<1250, 256, 0, stream>>>(agg2, W_out, b_out, out);
}

// Round 20
// 131.357 us; speedup vs baseline: 1.0683x; 1.0683x over previous
//
#include <hip/hip_runtime.h>

#define N_NODES 40000
#define E_EDGES 640000
#define E_TOT   (E_EDGES + N_NODES)
#define SCAN_BLOCKS ((N_NODES + 255) / 256)   // 157
#define G1_BLOCKS 625                         // 64 rows per block (4 waves x 16)
#define HIST_BLOCKS ((E_EDGES + 255) / 256)   // 2500

typedef unsigned int uint;
typedef unsigned short ushort;
typedef __attribute__((ext_vector_type(8))) short short8v;   // 8 bf16 (4 VGPRs)
typedef __attribute__((ext_vector_type(4))) float f32x4;     // MFMA accumulator

// bf16 helpers (RNE pack, cheap unpack)
__device__ __forceinline__ ushort f2bf(float f) {
    uint u = __float_as_uint(f);
    u += 0x7FFFu + ((u >> 16) & 1u);
    return (ushort)(u >> 16);
}
__device__ __forceinline__ uint pk_bf(float lo, float hi) {
    return (uint)f2bf(lo) | ((uint)f2bf(hi) << 16);
}
__device__ __forceinline__ float bf_lo(uint w) { return __uint_as_float(w << 16); }
__device__ __forceinline__ float bf_hi(uint w) { return __uint_as_float(w & 0xFFFF0000u); }
__device__ __forceinline__ float bf2f(ushort v) { return __uint_as_float((uint)v << 16); }

// ===========================================================================
// prep: blocks 0..39  -> cnt[i] = 1 (self-loop baked in -> occupies rank 0)
//       blocks 40..47 -> pack W1 (f32 128x128) into MFMA B-fragment order
// ===========================================================================
__global__ __launch_bounds__(256) void prep_kernel(
    const float* __restrict__ W1, int4* __restrict__ cnt4, ushort* __restrict__ Wf)
{
    if (blockIdx.x < 40) {
        const int i = blockIdx.x * 256 + threadIdx.x;
        if (i < 40064 / 4) cnt4[i] = make_int4(1, 1, 1, 1);
        return;
    }
    const int s = (blockIdx.x - 40) * 256 + threadIdx.x;   // 0..2047
    if (s >= 2048) return;
    const int kk = s >> 9;          // K-step (32 per step)
    const int rem = s & 511;
    const int ct = rem >> 6;        // column tile (16 cols)
    const int l = rem & 63;         // lane
    const int k0 = kk * 32 + (l >> 4) * 8;
    const int col = ct * 16 + (l & 15);
    uint4 o;
    o.x = pk_bf(W1[(k0 + 0) * 128 + col], W1[(k0 + 1) * 128 + col]);
    o.y = pk_bf(W1[(k0 + 2) * 128 + col], W1[(k0 + 3) * 128 + col]);
    o.z = pk_bf(W1[(k0 + 4) * 128 + col], W1[(k0 + 5) * 128 + col]);
    o.w = pk_bf(W1[(k0 + 6) * 128 + col], W1[(k0 + 7) * 128 + col]);
    ((uint4*)Wf)[s] = o;
}

// ===========================================================================
// FUSED gemm1 (MFMA) ∥ hist+rank (block-range partition, independent):
//   blocks [0, G1_BLOCKS)            -> MFMA GEMM tile (needs only x, Wf)
//   blocks [G1_BLOCKS, +HIST_BLOCKS) -> histogram; rank[e] = old count
// ===========================================================================
__global__ __launch_bounds__(256) void gemm1_hist_kernel(
    const float* __restrict__ x, const ushort* __restrict__ Wf,
    const float* __restrict__ a_src, const float* __restrict__ a_dst,
    ushort* __restrict__ h1b, float* __restrict__ asrc, float* __restrict__ adst,
    const int* __restrict__ eidx, int* __restrict__ cnt, int* __restrict__ rank)
{
    if (blockIdx.x >= G1_BLOCKS) {
        // ---- hist partition: 1 edge/thread; record rank ----
        const int e = (blockIdx.x - G1_BLOCKS) * 256 + threadIdx.x;
        if (e < E_EDGES)
            rank[e] = atomicAdd(&cnt[eidx[E_EDGES + e]], 1);
        return;
    }

    // ---- gemm1 partition: one wave = 16 rows x 128 cols, K-loop 4 x 32 ----
    const int wv = threadIdx.x >> 6;
    const int lane = threadIdx.x & 63;
    const int rowbase = blockIdx.x * 64 + wv * 16;
    const int arow = rowbase + (lane & 15);
    const int kof = (lane >> 4) * 8;

    f32x4 acc0 = {0.f,0.f,0.f,0.f}, acc1 = {0.f,0.f,0.f,0.f};
    f32x4 acc2 = {0.f,0.f,0.f,0.f}, acc3 = {0.f,0.f,0.f,0.f};
    f32x4 acc4 = {0.f,0.f,0.f,0.f}, acc5 = {0.f,0.f,0.f,0.f};
    f32x4 acc6 = {0.f,0.f,0.f,0.f}, acc7 = {0.f,0.f,0.f,0.f};

    const short8v* WfV = (const short8v*)Wf;
#pragma unroll
    for (int kk = 0; kk < 4; ++kk) {
        const float* ap = &x[(size_t)arow * 128 + kk * 32 + kof];
        const float4 a0 = *(const float4*)ap;
        const float4 a1 = *(const float4*)(ap + 4);
        short8v af;
        af[0] = (short)f2bf(a0.x); af[1] = (short)f2bf(a0.y);
        af[2] = (short)f2bf(a0.z); af[3] = (short)f2bf(a0.w);
        af[4] = (short)f2bf(a1.x); af[5] = (short)f2bf(a1.y);
        af[6] = (short)f2bf(a1.z); af[7] = (short)f2bf(a1.w);
        const int base = kk * 8 * 64 + lane;
        acc0 = __builtin_amdgcn_mfma_f32_16x16x32_bf16(af, WfV[base + 0 * 64], acc0, 0, 0, 0);
        acc1 = __builtin_amdgcn_mfma_f32_16x16x32_bf16(af, WfV[base + 1 * 64], acc1, 0, 0, 0);
        acc2 = __builtin_amdgcn_mfma_f32_16x16x32_bf16(af, WfV[base + 2 * 64], acc2, 0, 0, 0);
        acc3 = __builtin_amdgcn_mfma_f32_16x16x32_bf16(af, WfV[base + 3 * 64], acc3, 0, 0, 0);
        acc4 = __builtin_amdgcn_mfma_f32_16x16x32_bf16(af, WfV[base + 4 * 64], acc4, 0, 0, 0);
        acc5 = __builtin_amdgcn_mfma_f32_16x16x32_bf16(af, WfV[base + 5 * 64], acc5, 0, 0, 0);
        acc6 = __builtin_amdgcn_mfma_f32_16x16x32_bf16(af, WfV[base + 6 * 64], acc6, 0, 0, 0);
        acc7 = __builtin_amdgcn_mfma_f32_16x16x32_bf16(af, WfV[base + 7 * 64], acc7, 0, 0, 0);
    }

    const int cl = lane & 15;   // col within tile
    const int rg = lane >> 4;   // row group
    float csA[8], cdA[8];
#pragma unroll
    for (int ct = 0; ct < 8; ++ct) {
        csA[ct] = a_src[(ct >> 1) * 32 + (ct & 1) * 16 + cl];
        cdA[ct] = a_dst[(ct >> 1) * 32 + (ct & 1) * 16 + cl];
    }
    const f32x4 accv[8] = { acc0, acc1, acc2, acc3, acc4, acc5, acc6, acc7 };
#pragma unroll
    for (int r = 0; r < 4; ++r) {
        const int n = rowbase + rg * 4 + r;
        ushort* hrow = &h1b[(size_t)n * 128 + cl];
#pragma unroll
        for (int ct = 0; ct < 8; ++ct) hrow[ct * 16] = f2bf(accv[ct][r]);
#pragma unroll
        for (int h = 0; h < 4; ++h) {
            float ps = accv[2 * h][r] * csA[2 * h] + accv[2 * h + 1][r] * csA[2 * h + 1];
            float pd = accv[2 * h][r] * cdA[2 * h] + accv[2 * h + 1][r] * cdA[2 * h + 1];
            ps += __shfl_xor(ps, 1); ps += __shfl_xor(ps, 2);
            ps += __shfl_xor(ps, 4); ps += __shfl_xor(ps, 8);
            pd += __shfl_xor(pd, 1); pd += __shfl_xor(pd, 2);
            pd += __shfl_xor(pd, 4); pd += __shfl_xor(pd, 8);
            if (cl == 0) { asrc[n * 4 + h] = ps; adst[n * 4 + h] = pd; }
        }
    }
}

// ===========================================================================
// scanA: block-local exclusive scan (incl. boundary slot); block total -> bsum.
// ===========================================================================
__global__ __launch_bounds__(256) void scanA_kernel(
    const int* __restrict__ cnt, int* __restrict__ rowptr, int* __restrict__ bsum)
{
    const int i = blockIdx.x * 256 + threadIdx.x;
    const int lane = threadIdx.x & 63;
    const int wave = threadIdx.x >> 6;
    const int v = (i < N_NODES) ? cnt[i] : 0;
    int incl = v;
#pragma unroll
    for (int off = 1; off < 64; off <<= 1) {
        int u = __shfl_up(incl, off);
        if (lane >= off) incl += u;
    }
    __shared__ int ws[4];
    if (lane == 63) ws[wave] = incl;
    __syncthreads();
    int woff = 0;
    if (wave > 0) woff += ws[0];
    if (wave > 1) woff += ws[1];
    if (wave > 2) woff += ws[2];
    if (i <= N_NODES) rowptr[i] = woff + incl - v;   // block-local exclusive
    if (threadIdx.x == 255) bsum[blockIdx.x] = woff + incl;
}

// Single block: exclusive scan of the 157 block sums in place.
__global__ __launch_bounds__(256) void scanB_kernel(int* __restrict__ bsum)
{
    const int t = threadIdx.x;
    const int lane = t & 63;
    const int wave = t >> 6;
    const int v = (t < SCAN_BLOCKS) ? bsum[t] : 0;
    int incl = v;
#pragma unroll
    for (int off = 1; off < 64; off <<= 1) {
        int u = __shfl_up(incl, off);
        if (lane >= off) incl += u;
    }
    __shared__ int ws[4];
    if (lane == 63) ws[wave] = incl;
    __syncthreads();
    int woff = 0;
    if (wave > 0) woff += ws[0];
    if (wave > 1) woff += ws[1];
    if (wave > 2) woff += ws[2];
    if (t < SCAN_BLOCKS) bsum[t] = woff + incl - v;  // exclusive
}

// ===========================================================================
// fill (ATOMIC-FREE): esrc[rowptr[d] + bsum[d>>8] + rank[e]] = s.
// ===========================================================================
__global__ __launch_bounds__(256) void fill_kernel(
    const int* __restrict__ eidx, const int* __restrict__ rowptr,
    const int* __restrict__ bsum, const int* __restrict__ rank,
    int* __restrict__ esrc)
{
    const int e = blockIdx.x * 256 + threadIdx.x;
    if (e >= E_TOT) return;
    int s, d, r;
    if (e < E_EDGES) { s = eidx[e]; d = eidx[E_EDGES + e]; r = rank[e]; }
    else             { s = d = e - E_EDGES; r = 0; }
    esrc[rowptr[d] + bsum[d >> 8] + r] = s;
}

// ===========================================================================
// Gather pass 1: 32 lanes per dst node (2 nodes/wave, 16 rows in flight).
// Each lane covers 4 bf16 channels (uint2 8B load); 8-deep pipeline;
// fused normalize + bias + ELU (float4 store).
// ===========================================================================
__global__ __launch_bounds__(256) void gather1_kernel(
    const int* __restrict__ rowptr, const int* __restrict__ bsum,
    const int* __restrict__ esrc, const float* __restrict__ asrc,
    const float* __restrict__ adst,
    const ushort* __restrict__ h1b, const float* __restrict__ b,
    float* __restrict__ agg)
{
    const int t = blockIdx.x * 256 + threadIdx.x;
    const int node = t >> 5;                 // grid exact: 5000*256/32 = 40000
    const int l32 = t & 31;                  // lane within node group
    const int head = l32 >> 3;               // 8 lanes per head
    const int cb = l32 * 4;                  // first of 4 bf16 channels
    const float ad = adst[node * 4 + head];
    const int beg = rowptr[node] + bsum[node >> 8];
    const int end = rowptr[node + 1] + bsum[(node + 1) >> 8];
    float acc0 = 0.f, acc1 = 0.f, acc2 = 0.f, acc3 = 0.f, den = 0.f;

    int i = beg;
    for (; i + 8 <= end; i += 8) {
        int s[8];
        float a[8];
        uint2 w[8];
#pragma unroll
        for (int j = 0; j < 8; ++j) s[j] = esrc[i + j];
#pragma unroll
        for (int j = 0; j < 8; ++j) a[j] = asrc[s[j] * 4 + head];
#pragma unroll
        for (int j = 0; j < 8; ++j)
            w[j] = *(const uint2*)&h1b[(size_t)s[j] * 128 + cb];
#pragma unroll
        for (int j = 0; j < 8; ++j) {
            float v = a[j] + ad; v = v > 0.f ? v : 0.2f * v;
            const float e = __expf(v);
            den += e;
            acc0 = fmaf(e, bf_lo(w[j].x), acc0);
            acc1 = fmaf(e, bf_hi(w[j].x), acc1);
            acc2 = fmaf(e, bf_lo(w[j].y), acc2);
            acc3 = fmaf(e, bf_hi(w[j].y), acc3);
        }
    }
    for (; i < end; ++i) {
        const int s = esrc[i];
        float av = asrc[s * 4 + head] + ad;
        av = av > 0.f ? av : 0.2f * av;
        const float ex = __expf(av);
        const uint2 w = *(const uint2*)&h1b[(size_t)s * 128 + cb];
        den += ex;
        acc0 = fmaf(ex, bf_lo(w.x), acc0);
        acc1 = fmaf(ex, bf_hi(w.x), acc1);
        acc2 = fmaf(ex, bf_lo(w.y), acc2);
        acc3 = fmaf(ex, bf_hi(w.y), acc3);
    }

    const float inv = 1.f / (den + 1e-16f);
    const float4 bv = *(const float4*)&b[cb];
    float o0 = acc0 * inv + bv.x;
    float o1 = acc1 * inv + bv.y;
    float o2 = acc2 * inv + bv.z;
    float o3 = acc3 * inv + bv.w;
    o0 = o0 > 0.f ? o0 : expm1f(o0);
    o1 = o1 > 0.f ? o1 : expm1f(o1);
    o2 = o2 > 0.f ? o2 : expm1f(o2);
    o3 = o3 > 0.f ? o3 : expm1f(o3);
    *(float4*)&agg[(size_t)node * 128 + cb] = make_float4(o0, o1, o2, o3);
}

// ===========================================================================
// GEMM2: h2 = hin @ W2 [40000x128 @ 128x32]; h2 stored bf16 (halves gather2
// traffic; 2.6 MB -> cache-resident); fused attention coeffs (1 head).
// ===========================================================================
__global__ __launch_bounds__(256) void gemm2_kernel(
    const float* __restrict__ hin, const float* __restrict__ W,
    const float* __restrict__ a_src, const float* __restrict__ a_dst,
    ushort* __restrict__ h2b, float* __restrict__ asrc, float* __restrict__ adst)
{
    __shared__ float Ws[128 * 32];   // 16 KB
    {
        const float4* Wg = (const float4*)W;
        float4* Wl = (float4*)Ws;
        for (int i = threadIdx.x; i < 128 * 32 / 4; i += 256) Wl[i] = Wg[i];
    }
    __syncthreads();
    const int row0 = blockIdx.x * 64;
    const int tx = threadIdx.x & 7;
    const int ty = threadIdx.x >> 3;

    float acc[2][4];
#pragma unroll
    for (int r = 0; r < 2; ++r)
#pragma unroll
        for (int c = 0; c < 4; ++c) acc[r][c] = 0.f;

    for (int k0 = 0; k0 < 128; k0 += 4) {
        float xv[2][4];
#pragma unroll
        for (int r = 0; r < 2; ++r) {
            float4 t = *(const float4*)&hin[(size_t)(row0 + ty * 2 + r) * 128 + k0];
            xv[r][0] = t.x; xv[r][1] = t.y; xv[r][2] = t.z; xv[r][3] = t.w;
        }
#pragma unroll
        for (int kk = 0; kk < 4; ++kk) {
            float4 w = *(const float4*)&Ws[(k0 + kk) * 32 + tx * 4];
            float wreg[4] = { w.x, w.y, w.z, w.w };
#pragma unroll
            for (int r = 0; r < 2; ++r)
#pragma unroll
                for (int c = 0; c < 4; ++c)
                    acc[r][c] = fmaf(xv[r][kk], wreg[c], acc[r][c]);
        }
    }

    float as[4], ad[4];
#pragma unroll
    for (int c = 0; c < 4; ++c) {
        as[c] = a_src[tx * 4 + c];
        ad[c] = a_dst[tx * 4 + c];
    }
#pragma unroll
    for (int r = 0; r < 2; ++r) {
        const int n = row0 + ty * 2 + r;
        uint2 o;
        o.x = pk_bf(acc[r][0], acc[r][1]);
        o.y = pk_bf(acc[r][2], acc[r][3]);
        *(uint2*)&h2b[(size_t)n * 32 + tx * 4] = o;
        float ps = 0.f, pd = 0.f;
#pragma unroll
        for (int c = 0; c < 4; ++c) {
            ps = fmaf(acc[r][c], as[c], ps);
            pd = fmaf(acc[r][c], ad[c], pd);
        }
        ps += __shfl_xor(ps, 1); ps += __shfl_xor(ps, 2); ps += __shfl_xor(ps, 4);
        pd += __shfl_xor(pd, 1); pd += __shfl_xor(pd, 2); pd += __shfl_xor(pd, 4);
        if ((threadIdx.x & 7) == 0) { asrc[n] = ps; adst[n] = pd; }
    }
}

// ===========================================================================
// Gather pass 2: 32 lanes per dst node (R18 layout), bf16 h2 rows (64 B,
// ushort load per lane); 8-deep pipeline; fused norm + bias + ELU.
// ===========================================================================
__global__ __launch_bounds__(256) void gather2_kernel(
    const int* __restrict__ rowptr, const int* __restrict__ bsum,
    const int* __restrict__ esrc,
    const float* __restrict__ asrc, const float* __restrict__ adst,
    const ushort* __restrict__ h2b, const float* __restrict__ b,
    float* __restrict__ agg)
{
    const int t = blockIdx.x * 256 + threadIdx.x;
    const int node = t >> 5;
    const int c = t & 31;
    if (node >= N_NODES) return;
    const float ad = adst[node];
    const int beg = rowptr[node] + bsum[node >> 8];
    const int end = rowptr[node + 1] + bsum[(node + 1) >> 8];
    float acc = 0.f, den = 0.f;

    int i = beg;
    for (; i + 8 <= end; i += 8) {
        int s[8];
        float a[8];
        ushort w[8];
#pragma unroll
        for (int j = 0; j < 8; ++j) s[j] = esrc[i + j];
#pragma unroll
        for (int j = 0; j < 8; ++j) a[j] = asrc[s[j]];
#pragma unroll
        for (int j = 0; j < 8; ++j) w[j] = h2b[(size_t)s[j] * 32 + c];
#pragma unroll
        for (int j = 0; j < 8; ++j) {
            float v = a[j] + ad; v = v > 0.f ? v : 0.2f * v;
            const float e = __expf(v);
            den += e;
            acc = fmaf(e, bf2f(w[j]), acc);
        }
    }
    for (; i < end; ++i) {
        const int s = esrc[i];
        float av = asrc[s] + ad;
        av = av > 0.f ? av : 0.2f * av;
        const float ex = __expf(av);
        den += ex;
        acc = fmaf(ex, bf2f(h2b[(size_t)s * 32 + c]), acc);
    }

    const float inv = 1.f / (den + 1e-16f);
    float o = acc * inv + b[c];
    o = o > 0.f ? o : expm1f(o);
    agg[(size_t)node * 32 + c] = o;
}

// ===========================================================================
// Output GEMM: out = h3 @ W_out + b_out  [40000x32 @ 32x112]
// ===========================================================================
__global__ __launch_bounds__(256) void out_gemm_kernel(
    const float* __restrict__ h3, const float* __restrict__ W,
    const float* __restrict__ b, float* __restrict__ out)
{
    __shared__ float Ws[32 * 112];   // 14 KB
    {
        const float4* Wg = (const float4*)W;
        float4* Wl = (float4*)Ws;
        for (int i = threadIdx.x; i < 32 * 112 / 4; i += 256) Wl[i] = Wg[i];
    }
    __syncthreads();
    const int row0 = blockIdx.x * 32;
    const int tc = threadIdx.x & 15;
    const int tr = threadIdx.x >> 4;

    float acc[2][7];
#pragma unroll
    for (int r = 0; r < 2; ++r)
#pragma unroll
        for (int c = 0; c < 7; ++c) acc[r][c] = 0.f;

    for (int k0 = 0; k0 < 32; k0 += 4) {
        float xv[2][4];
#pragma unroll
        for (int r = 0; r < 2; ++r) {
            float4 t = *(const float4*)&h3[(size_t)(row0 + tr * 2 + r) * 32 + k0];
            xv[r][0] = t.x; xv[r][1] = t.y; xv[r][2] = t.z; xv[r][3] = t.w;
        }
#pragma unroll
        for (int kk = 0; kk < 4; ++kk) {
            float wv[7];
#pragma unroll
            for (int c = 0; c < 7; ++c) wv[c] = Ws[(k0 + kk) * 112 + tc * 7 + c];
#pragma unroll
            for (int r = 0; r < 2; ++r)
#pragma unroll
                for (int c = 0; c < 7; ++c)
                    acc[r][c] = fmaf(xv[r][kk], wv[c], acc[r][c]);
        }
    }
#pragma unroll
    for (int r = 0; r < 2; ++r) {
        const int n = row0 + tr * 2 + r;
#pragma unroll
        for (int c = 0; c < 7; ++c)
            out[(size_t)n * 112 + tc * 7 + c] = acc[r][c] + b[tc * 7 + c];
    }
}

// ===========================================================================
extern "C" void kernel_launch(void* const* d_in, const int* in_sizes, int n_in,
                              void* d_out, int out_size, void* d_ws, size_t ws_size,
                              hipStream_t stream) {
    const float* x      = (const float*)d_in[0];
    const int*   eidx   = (const int*)d_in[1];
    const float* W1     = (const float*)d_in[2];
    const float* a_src1 = (const float*)d_in[3];
    const float* a_dst1 = (const float*)d_in[4];
    const float* b1     = (const float*)d_in[5];
    const float* W2     = (const float*)d_in[6];
    const float* a_src2 = (const float*)d_in[7];
    const float* a_dst2 = (const float*)d_in[8];
    const float* b2     = (const float*)d_in[9];
    const float* W_out  = (const float*)d_in[10];
    const float* b_out  = (const float*)d_in[11];
    float* out = (float*)d_out;

    // ---- workspace layout (~38 MB) ----
    int* rowptr = (int*)d_ws;                 // 40064 (uses [0..40000])
    int* cnt    = rowptr + 40064;             // 40064 histogram (init = 1)
    int* bsum   = cnt + 40064;                // 192 block sums (exclusive)
    int* rank   = bsum + 192;                 // 680000 per-edge bucket rank
    ushort* Wf  = (ushort*)(rank + 680000);   // 16384 bf16 (32 KB, frag-ordered W1)
    int* esrc   = (int*)(Wf + 16384);         // 680000 CSR edge sources
    ushort* h1b  = (ushort*)(esrc + 680000);  // 40000*128 bf16
    float* asrc1 = (float*)(h1b + 5120000);   // 40000*4
    float* adst1 = asrc1 + 160000;            // 40000*4
    float* agg1  = adst1 + 160000;            // 40000*128
    // after gather1, h1b region is dead -> layer-2 buffers overlay it
    ushort* h2b  = (ushort*)h1b;              // 40000*32 bf16
    float* asrc2 = (float*)(h2b + 1280000);   // 40000
    float* adst2 = asrc2 + 40000;             // 40000
    float* agg2  = adst2 + 40000;             // 40000*32

    // cnt=1 init (self-loops -> rank 0) + W1 -> bf16 fragment pack
    prep_kernel<<<48, 256, 0, stream>>>(W1, (int4*)cnt, Wf);

    // Layer-1 GEMM (MFMA) ∥ histogram-with-rank — independent block partitions
    gemm1_hist_kernel<<<G1_BLOCKS + HIST_BLOCKS, 256, 0, stream>>>(
        x, Wf, a_src1, a_dst1, h1b, asrc1, adst1, eidx, cnt, rank);

    // CSR scan
    scanA_kernel<<<SCAN_BLOCKS, 256, 0, stream>>>(cnt, rowptr, bsum);
    scanB_kernel<<<1, 256, 0, stream>>>(bsum);

    // Atomic-free bucket fill
    fill_kernel<<<(E_TOT + 255) / 256, 256, 0, stream>>>(
        eidx, rowptr, bsum, rank, esrc);

    // Layer 1 aggregate (2 nodes/wave, 16 rows in flight)
    gather1_kernel<<<5000, 256, 0, stream>>>(rowptr, bsum, esrc, asrc1, adst1,
                                             h1b, b1, agg1);

    // Layer 2
    gemm2_kernel<<<625, 256, 0, stream>>>(agg1, W2, a_src2, a_dst2, h2b, asrc2, adst2);
    gather2_kernel<<<5000, 256, 0, stream>>>(rowptr, bsum, esrc, asrc2, adst2,
                                             h2b, b2, agg2);

    // Output projection
    out_gemm_kernel<<<1250, 256, 0, stream>>>(agg2, W_out, b_out, out);
}

// Round 21
// 119.133 us; speedup vs baseline: 1.1780x; 1.1026x over previous
//
#include <hip/hip_runtime.h>

#define N_NODES 40000
#define E_EDGES 640000
#define E_TOT   (E_EDGES + N_NODES)
#define SCAN_BLOCKS ((N_NODES + 255) / 256)   // 157
#define G1_BLOCKS 625                         // 64 rows per block (4 waves x 16)
#define HIST_BLOCKS ((E_EDGES + 255) / 256)   // 2500

typedef unsigned int uint;
typedef unsigned short ushort;
typedef __attribute__((ext_vector_type(8))) short short8v;   // 8 bf16 (4 VGPRs)
typedef __attribute__((ext_vector_type(4))) float f32x4;     // MFMA accumulator

// bf16 helpers (RNE pack, cheap unpack)
__device__ __forceinline__ ushort f2bf(float f) {
    uint u = __float_as_uint(f);
    u += 0x7FFFu + ((u >> 16) & 1u);
    return (ushort)(u >> 16);
}
__device__ __forceinline__ uint pk_bf(float lo, float hi) {
    return (uint)f2bf(lo) | ((uint)f2bf(hi) << 16);
}
__device__ __forceinline__ float bf_lo(uint w) { return __uint_as_float(w << 16); }
__device__ __forceinline__ float bf_hi(uint w) { return __uint_as_float(w & 0xFFFF0000u); }
__device__ __forceinline__ float bf2f(ushort v) { return __uint_as_float((uint)v << 16); }

// ===========================================================================
// prep: blocks 0..39  -> cnt[i] = 1 (self-loop baked in -> occupies rank 0)
//       blocks 40..47 -> pack W1 (128x128) into MFMA B-fragment order
//       blocks 48..49 -> pack W2 (128x32), 2 column tiles x 4 K-steps
//       blocks 50..51 -> pack W_out (32x112), 7 column tiles x 1 K-step
// Fragment layout (m89-verified): slot holds 8 bf16 B[k0+j][col],
// k0 = kk*32 + (l>>4)*8, col = ct*16 + (l&15).
// ===========================================================================
__global__ __launch_bounds__(256) void prep_kernel(
    const float* __restrict__ W1, const float* __restrict__ W2,
    const float* __restrict__ W_out,
    int4* __restrict__ cnt4, ushort* __restrict__ Wf,
    ushort* __restrict__ Wf2, ushort* __restrict__ Wfo)
{
    if (blockIdx.x < 40) {
        const int i = blockIdx.x * 256 + threadIdx.x;
        if (i < 40064 / 4) cnt4[i] = make_int4(1, 1, 1, 1);
        return;
    }
    if (blockIdx.x < 48) {
        const int s = (blockIdx.x - 40) * 256 + threadIdx.x;   // 0..2047
        const int kk = s >> 9;
        const int rem = s & 511;
        const int ct = rem >> 6;
        const int l = rem & 63;
        const int k0 = kk * 32 + (l >> 4) * 8;
        const int col = ct * 16 + (l & 15);
        uint4 o;
        o.x = pk_bf(W1[(k0 + 0) * 128 + col], W1[(k0 + 1) * 128 + col]);
        o.y = pk_bf(W1[(k0 + 2) * 128 + col], W1[(k0 + 3) * 128 + col]);
        o.z = pk_bf(W1[(k0 + 4) * 128 + col], W1[(k0 + 5) * 128 + col]);
        o.w = pk_bf(W1[(k0 + 6) * 128 + col], W1[(k0 + 7) * 128 + col]);
        ((uint4*)Wf)[s] = o;
        return;
    }
    if (blockIdx.x < 50) {
        const int s = (blockIdx.x - 48) * 256 + threadIdx.x;   // 0..511
        const int kk = s >> 7;          // 4 K-steps
        const int rem = s & 127;
        const int ct = rem >> 6;        // 2 column tiles
        const int l = rem & 63;
        const int k0 = kk * 32 + (l >> 4) * 8;
        const int col = ct * 16 + (l & 15);
        uint4 o;
        o.x = pk_bf(W2[(k0 + 0) * 32 + col], W2[(k0 + 1) * 32 + col]);
        o.y = pk_bf(W2[(k0 + 2) * 32 + col], W2[(k0 + 3) * 32 + col]);
        o.z = pk_bf(W2[(k0 + 4) * 32 + col], W2[(k0 + 5) * 32 + col]);
        o.w = pk_bf(W2[(k0 + 6) * 32 + col], W2[(k0 + 7) * 32 + col]);
        ((uint4*)Wf2)[s] = o;
        return;
    }
    {
        const int s = (blockIdx.x - 50) * 256 + threadIdx.x;   // 0..511, valid <448
        if (s >= 448) return;
        const int ct = s >> 6;          // 7 column tiles
        const int l = s & 63;
        const int k0 = (l >> 4) * 8;    // K = 32, single step
        const int col = ct * 16 + (l & 15);
        uint4 o;
        o.x = pk_bf(W_out[(k0 + 0) * 112 + col], W_out[(k0 + 1) * 112 + col]);
        o.y = pk_bf(W_out[(k0 + 2) * 112 + col], W_out[(k0 + 3) * 112 + col]);
        o.z = pk_bf(W_out[(k0 + 4) * 112 + col], W_out[(k0 + 5) * 112 + col]);
        o.w = pk_bf(W_out[(k0 + 6) * 112 + col], W_out[(k0 + 7) * 112 + col]);
        ((uint4*)Wfo)[s] = o;
    }
}

// ===========================================================================
// FUSED gemm1 (MFMA) ∥ hist+rank (block-range partition, independent).
// ===========================================================================
__global__ __launch_bounds__(256) void gemm1_hist_kernel(
    const float* __restrict__ x, const ushort* __restrict__ Wf,
    const float* __restrict__ a_src, const float* __restrict__ a_dst,
    ushort* __restrict__ h1b, float* __restrict__ asrc, float* __restrict__ adst,
    const int* __restrict__ eidx, int* __restrict__ cnt, int* __restrict__ rank)
{
    if (blockIdx.x >= G1_BLOCKS) {
        const int e = (blockIdx.x - G1_BLOCKS) * 256 + threadIdx.x;
        if (e < E_EDGES)
            rank[e] = atomicAdd(&cnt[eidx[E_EDGES + e]], 1);
        return;
    }

    const int wv = threadIdx.x >> 6;
    const int lane = threadIdx.x & 63;
    const int rowbase = blockIdx.x * 64 + wv * 16;
    const int arow = rowbase + (lane & 15);
    const int kof = (lane >> 4) * 8;

    f32x4 acc0 = {0.f,0.f,0.f,0.f}, acc1 = {0.f,0.f,0.f,0.f};
    f32x4 acc2 = {0.f,0.f,0.f,0.f}, acc3 = {0.f,0.f,0.f,0.f};
    f32x4 acc4 = {0.f,0.f,0.f,0.f}, acc5 = {0.f,0.f,0.f,0.f};
    f32x4 acc6 = {0.f,0.f,0.f,0.f}, acc7 = {0.f,0.f,0.f,0.f};

    const short8v* WfV = (const short8v*)Wf;
#pragma unroll
    for (int kk = 0; kk < 4; ++kk) {
        const float* ap = &x[(size_t)arow * 128 + kk * 32 + kof];
        const float4 a0 = *(const float4*)ap;
        const float4 a1 = *(const float4*)(ap + 4);
        short8v af;
        af[0] = (short)f2bf(a0.x); af[1] = (short)f2bf(a0.y);
        af[2] = (short)f2bf(a0.z); af[3] = (short)f2bf(a0.w);
        af[4] = (short)f2bf(a1.x); af[5] = (short)f2bf(a1.y);
        af[6] = (short)f2bf(a1.z); af[7] = (short)f2bf(a1.w);
        const int base = kk * 8 * 64 + lane;
        acc0 = __builtin_amdgcn_mfma_f32_16x16x32_bf16(af, WfV[base + 0 * 64], acc0, 0, 0, 0);
        acc1 = __builtin_amdgcn_mfma_f32_16x16x32_bf16(af, WfV[base + 1 * 64], acc1, 0, 0, 0);
        acc2 = __builtin_amdgcn_mfma_f32_16x16x32_bf16(af, WfV[base + 2 * 64], acc2, 0, 0, 0);
        acc3 = __builtin_amdgcn_mfma_f32_16x16x32_bf16(af, WfV[base + 3 * 64], acc3, 0, 0, 0);
        acc4 = __builtin_amdgcn_mfma_f32_16x16x32_bf16(af, WfV[base + 4 * 64], acc4, 0, 0, 0);
        acc5 = __builtin_amdgcn_mfma_f32_16x16x32_bf16(af, WfV[base + 5 * 64], acc5, 0, 0, 0);
        acc6 = __builtin_amdgcn_mfma_f32_16x16x32_bf16(af, WfV[base + 6 * 64], acc6, 0, 0, 0);
        acc7 = __builtin_amdgcn_mfma_f32_16x16x32_bf16(af, WfV[base + 7 * 64], acc7, 0, 0, 0);
    }

    const int cl = lane & 15;
    const int rg = lane >> 4;
    float csA[8], cdA[8];
#pragma unroll
    for (int ct = 0; ct < 8; ++ct) {
        csA[ct] = a_src[(ct >> 1) * 32 + (ct & 1) * 16 + cl];
        cdA[ct] = a_dst[(ct >> 1) * 32 + (ct & 1) * 16 + cl];
    }
    const f32x4 accv[8] = { acc0, acc1, acc2, acc3, acc4, acc5, acc6, acc7 };
#pragma unroll
    for (int r = 0; r < 4; ++r) {
        const int n = rowbase + rg * 4 + r;
        ushort* hrow = &h1b[(size_t)n * 128 + cl];
#pragma unroll
        for (int ct = 0; ct < 8; ++ct) hrow[ct * 16] = f2bf(accv[ct][r]);
#pragma unroll
        for (int h = 0; h < 4; ++h) {
            float ps = accv[2 * h][r] * csA[2 * h] + accv[2 * h + 1][r] * csA[2 * h + 1];
            float pd = accv[2 * h][r] * cdA[2 * h] + accv[2 * h + 1][r] * cdA[2 * h + 1];
            ps += __shfl_xor(ps, 1); ps += __shfl_xor(ps, 2);
            ps += __shfl_xor(ps, 4); ps += __shfl_xor(ps, 8);
            pd += __shfl_xor(pd, 1); pd += __shfl_xor(pd, 2);
            pd += __shfl_xor(pd, 4); pd += __shfl_xor(pd, 8);
            if (cl == 0) { asrc[n * 4 + h] = ps; adst[n * 4 + h] = pd; }
        }
    }
}

// ===========================================================================
// scanA / scanB (split, battle-tested).
// ===========================================================================
__global__ __launch_bounds__(256) void scanA_kernel(
    const int* __restrict__ cnt, int* __restrict__ rowptr, int* __restrict__ bsum)
{
    const int i = blockIdx.x * 256 + threadIdx.x;
    const int lane = threadIdx.x & 63;
    const int wave = threadIdx.x >> 6;
    const int v = (i < N_NODES) ? cnt[i] : 0;
    int incl = v;
#pragma unroll
    for (int off = 1; off < 64; off <<= 1) {
        int u = __shfl_up(incl, off);
        if (lane >= off) incl += u;
    }
    __shared__ int ws[4];
    if (lane == 63) ws[wave] = incl;
    __syncthreads();
    int woff = 0;
    if (wave > 0) woff += ws[0];
    if (wave > 1) woff += ws[1];
    if (wave > 2) woff += ws[2];
    if (i <= N_NODES) rowptr[i] = woff + incl - v;
    if (threadIdx.x == 255) bsum[blockIdx.x] = woff + incl;
}

__global__ __launch_bounds__(256) void scanB_kernel(int* __restrict__ bsum)
{
    const int t = threadIdx.x;
    const int lane = t & 63;
    const int wave = t >> 6;
    const int v = (t < SCAN_BLOCKS) ? bsum[t] : 0;
    int incl = v;
#pragma unroll
    for (int off = 1; off < 64; off <<= 1) {
        int u = __shfl_up(incl, off);
        if (lane >= off) incl += u;
    }
    __shared__ int ws[4];
    if (lane == 63) ws[wave] = incl;
    __syncthreads();
    int woff = 0;
    if (wave > 0) woff += ws[0];
    if (wave > 1) woff += ws[1];
    if (wave > 2) woff += ws[2];
    if (t < SCAN_BLOCKS) bsum[t] = woff + incl - v;
}

// ===========================================================================
// fill (ATOMIC-FREE): esrc[rowptr[d] + bsum[d>>8] + rank[e]] = s.
// ===========================================================================
__global__ __launch_bounds__(256) void fill_kernel(
    const int* __restrict__ eidx, const int* __restrict__ rowptr,
    const int* __restrict__ bsum, const int* __restrict__ rank,
    int* __restrict__ esrc)
{
    const int e = blockIdx.x * 256 + threadIdx.x;
    if (e >= E_TOT) return;
    int s, d, r;
    if (e < E_EDGES) { s = eidx[e]; d = eidx[E_EDGES + e]; r = rank[e]; }
    else             { s = d = e - E_EDGES; r = 0; }
    esrc[rowptr[d] + bsum[d >> 8] + r] = s;
}

// ===========================================================================
// Gather pass 1: 32 lanes per dst node (2 nodes/wave); bf16 rows; 8-deep
// pipeline; fused norm + bias + ELU; agg1 stored bf16 (feeds MFMA gemm2).
// ===========================================================================
__global__ __launch_bounds__(256) void gather1_kernel(
    const int* __restrict__ rowptr, const int* __restrict__ bsum,
    const int* __restrict__ esrc, const float* __restrict__ asrc,
    const float* __restrict__ adst,
    const ushort* __restrict__ h1b, const float* __restrict__ b,
    ushort* __restrict__ agg1b)
{
    const int t = blockIdx.x * 256 + threadIdx.x;
    const int node = t >> 5;                 // grid exact: 5000*256/32 = 40000
    const int l32 = t & 31;
    const int head = l32 >> 3;
    const int cb = l32 * 4;
    const float ad = adst[node * 4 + head];
    const int beg = rowptr[node] + bsum[node >> 8];
    const int end = rowptr[node + 1] + bsum[(node + 1) >> 8];
    float acc0 = 0.f, acc1 = 0.f, acc2 = 0.f, acc3 = 0.f, den = 0.f;

    int i = beg;
    for (; i + 8 <= end; i += 8) {
        int s[8];
        float a[8];
        uint2 w[8];
#pragma unroll
        for (int j = 0; j < 8; ++j) s[j] = esrc[i + j];
#pragma unroll
        for (int j = 0; j < 8; ++j) a[j] = asrc[s[j] * 4 + head];
#pragma unroll
        for (int j = 0; j < 8; ++j)
            w[j] = *(const uint2*)&h1b[(size_t)s[j] * 128 + cb];
#pragma unroll
        for (int j = 0; j < 8; ++j) {
            float v = a[j] + ad; v = v > 0.f ? v : 0.2f * v;
            const float e = __expf(v);
            den += e;
            acc0 = fmaf(e, bf_lo(w[j].x), acc0);
            acc1 = fmaf(e, bf_hi(w[j].x), acc1);
            acc2 = fmaf(e, bf_lo(w[j].y), acc2);
            acc3 = fmaf(e, bf_hi(w[j].y), acc3);
        }
    }
    for (; i < end; ++i) {
        const int s = esrc[i];
        float av = asrc[s * 4 + head] + ad;
        av = av > 0.f ? av : 0.2f * av;
        const float ex = __expf(av);
        const uint2 w = *(const uint2*)&h1b[(size_t)s * 128 + cb];
        den += ex;
        acc0 = fmaf(ex, bf_lo(w.x), acc0);
        acc1 = fmaf(ex, bf_hi(w.x), acc1);
        acc2 = fmaf(ex, bf_lo(w.y), acc2);
        acc3 = fmaf(ex, bf_hi(w.y), acc3);
    }

    const float inv = 1.f / (den + 1e-16f);
    const float4 bv = *(const float4*)&b[cb];
    float o0 = acc0 * inv + bv.x;
    float o1 = acc1 * inv + bv.y;
    float o2 = acc2 * inv + bv.z;
    float o3 = acc3 * inv + bv.w;
    o0 = o0 > 0.f ? o0 : expm1f(o0);
    o1 = o1 > 0.f ? o1 : expm1f(o1);
    o2 = o2 > 0.f ? o2 : expm1f(o2);
    o3 = o3 > 0.f ? o3 : expm1f(o3);
    uint2 o;
    o.x = pk_bf(o0, o1);
    o.y = pk_bf(o2, o3);
    *(uint2*)&agg1b[(size_t)node * 128 + cb] = o;
}

// ===========================================================================
// GEMM2 (MFMA): h2 = agg1 @ W2  [40000x128 @ 128x32], bf16 in, f32 accum.
// One wave = 16 rows x 32 cols (2 tiles), K-loop 4 x 32. Zero LDS.
// h2 stored bf16; fused attention coeffs (1 head) from f32 accumulators.
// ===========================================================================
__global__ __launch_bounds__(256) void gemm2_kernel(
    const ushort* __restrict__ agg1b, const ushort* __restrict__ Wf2,
    const float* __restrict__ a_src, const float* __restrict__ a_dst,
    ushort* __restrict__ h2b, float* __restrict__ asrc, float* __restrict__ adst)
{
    const int wv = threadIdx.x >> 6;
    const int lane = threadIdx.x & 63;
    const int rowbase = blockIdx.x * 64 + wv * 16;
    const int arow = rowbase + (lane & 15);
    const int kof = (lane >> 4) * 8;

    f32x4 acc0 = {0.f,0.f,0.f,0.f}, acc1 = {0.f,0.f,0.f,0.f};
    const short8v* Wf2V = (const short8v*)Wf2;
#pragma unroll
    for (int kk = 0; kk < 4; ++kk) {
        const short8v af = *(const short8v*)&agg1b[(size_t)arow * 128 + kk * 32 + kof];
        const int base = kk * 2 * 64 + lane;
        acc0 = __builtin_amdgcn_mfma_f32_16x16x32_bf16(af, Wf2V[base], acc0, 0, 0, 0);
        acc1 = __builtin_amdgcn_mfma_f32_16x16x32_bf16(af, Wf2V[base + 64], acc1, 0, 0, 0);
    }

    const int cl = lane & 15;
    const int rg = lane >> 4;
    const float cs0 = a_src[cl], cs1 = a_src[16 + cl];
    const float cd0 = a_dst[cl], cd1 = a_dst[16 + cl];
#pragma unroll
    for (int r = 0; r < 4; ++r) {
        const int n = rowbase + rg * 4 + r;
        h2b[(size_t)n * 32 + cl]      = f2bf(acc0[r]);
        h2b[(size_t)n * 32 + 16 + cl] = f2bf(acc1[r]);
        float ps = acc0[r] * cs0 + acc1[r] * cs1;
        float pd = acc0[r] * cd0 + acc1[r] * cd1;
        ps += __shfl_xor(ps, 1); ps += __shfl_xor(ps, 2);
        ps += __shfl_xor(ps, 4); ps += __shfl_xor(ps, 8);
        pd += __shfl_xor(pd, 1); pd += __shfl_xor(pd, 2);
        pd += __shfl_xor(pd, 4); pd += __shfl_xor(pd, 8);
        if (cl == 0) { asrc[n] = ps; adst[n] = pd; }
    }
}

// ===========================================================================
// Gather pass 2: 32 lanes per dst node, bf16 h2 rows; 8-deep pipeline;
// fused norm + bias + ELU; agg2 stored bf16 (feeds MFMA out_gemm).
// ===========================================================================
__global__ __launch_bounds__(256) void gather2_kernel(
    const int* __restrict__ rowptr, const int* __restrict__ bsum,
    const int* __restrict__ esrc,
    const float* __restrict__ asrc, const float* __restrict__ adst,
    const ushort* __restrict__ h2b, const float* __restrict__ b,
    ushort* __restrict__ agg2b)
{
    const int t = blockIdx.x * 256 + threadIdx.x;
    const int node = t >> 5;
    const int c = t & 31;
    if (node >= N_NODES) return;
    const float ad = adst[node];
    const int beg = rowptr[node] + bsum[node >> 8];
    const int end = rowptr[node + 1] + bsum[(node + 1) >> 8];
    float acc = 0.f, den = 0.f;

    int i = beg;
    for (; i + 8 <= end; i += 8) {
        int s[8];
        float a[8];
        ushort w[8];
#pragma unroll
        for (int j = 0; j < 8; ++j) s[j] = esrc[i + j];
#pragma unroll
        for (int j = 0; j < 8; ++j) a[j] = asrc[s[j]];
#pragma unroll
        for (int j = 0; j < 8; ++j) w[j] = h2b[(size_t)s[j] * 32 + c];
#pragma unroll
        for (int j = 0; j < 8; ++j) {
            float v = a[j] + ad; v = v > 0.f ? v : 0.2f * v;
            const float e = __expf(v);
            den += e;
            acc = fmaf(e, bf2f(w[j]), acc);
        }
    }
    for (; i < end; ++i) {
        const int s = esrc[i];
        float av = asrc[s] + ad;
        av = av > 0.f ? av : 0.2f * av;
        const float ex = __expf(av);
        den += ex;
        acc = fmaf(ex, bf2f(h2b[(size_t)s * 32 + c]), acc);
    }

    const float inv = 1.f / (den + 1e-16f);
    float o = acc * inv + b[c];
    o = o > 0.f ? o : expm1f(o);
    agg2b[(size_t)node * 32 + c] = f2bf(o);
}

// ===========================================================================
// Output GEMM (MFMA): out = agg2 @ W_out + b_out  [40000x32 @ 32x112].
// One wave = 16 rows x 112 cols (7 tiles), single K-step of 32. Zero LDS.
// ===========================================================================
__global__ __launch_bounds__(256) void out_gemm_kernel(
    const ushort* __restrict__ agg2b, const ushort* __restrict__ Wfo,
    const float* __restrict__ b_out, float* __restrict__ out)
{
    const int wv = threadIdx.x >> 6;
    const int lane = threadIdx.x & 63;
    const int rowbase = blockIdx.x * 64 + wv * 16;
    const int arow = rowbase + (lane & 15);
    const int kof = (lane >> 4) * 8;

    const short8v af = *(const short8v*)&agg2b[(size_t)arow * 32 + kof];
    const short8v* WfoV = (const short8v*)Wfo;
    f32x4 acc[7];
#pragma unroll
    for (int ct = 0; ct < 7; ++ct) {
        f32x4 z = {0.f, 0.f, 0.f, 0.f};
        acc[ct] = __builtin_amdgcn_mfma_f32_16x16x32_bf16(af, WfoV[ct * 64 + lane], z, 0, 0, 0);
    }

    const int cl = lane & 15;
    const int rg = lane >> 4;
    float bo[7];
#pragma unroll
    for (int ct = 0; ct < 7; ++ct) bo[ct] = b_out[ct * 16 + cl];
#pragma unroll
    for (int r = 0; r < 4; ++r) {
        const int n = rowbase + rg * 4 + r;
        float* orow = &out[(size_t)n * 112 + cl];
#pragma unroll
        for (int ct = 0; ct < 7; ++ct) orow[ct * 16] = acc[ct][r] + bo[ct];
    }
}

// ===========================================================================
extern "C" void kernel_launch(void* const* d_in, const int* in_sizes, int n_in,
                              void* d_out, int out_size, void* d_ws, size_t ws_size,
                              hipStream_t stream) {
    const float* x      = (const float*)d_in[0];
    const int*   eidx   = (const int*)d_in[1];
    const float* W1     = (const float*)d_in[2];
    const float* a_src1 = (const float*)d_in[3];
    const float* a_dst1 = (const float*)d_in[4];
    const float* b1     = (const float*)d_in[5];
    const float* W2     = (const float*)d_in[6];
    const float* a_src2 = (const float*)d_in[7];
    const float* a_dst2 = (const float*)d_in[8];
    const float* b2     = (const float*)d_in[9];
    const float* W_out  = (const float*)d_in[10];
    const float* b_out  = (const float*)d_in[11];
    float* out = (float*)d_out;

    // ---- workspace layout (~30 MB) ----
    int* rowptr = (int*)d_ws;                 // 40064 (uses [0..40000])
    int* cnt    = rowptr + 40064;             // 40064 histogram (init = 1)
    int* bsum   = cnt + 40064;                // 192 block sums (exclusive)
    int* rank   = bsum + 192;                 // 680000 per-edge bucket rank
    ushort* Wf  = (ushort*)(rank + 680000);   // 16384 bf16 (W1 fragments)
    ushort* Wf2 = Wf + 16384;                 // 4096 bf16 (W2 fragments)
    ushort* Wfo = Wf2 + 4096;                 // 3584 bf16 (+pad 512) W_out fragments
    int* esrc   = (int*)(Wfo + 4096);         // 680000 CSR edge sources
    ushort* h1b  = (ushort*)(esrc + 680000);  // 40000*128 bf16
    float* asrc1 = (float*)(h1b + 5120000);   // 40000*4
    float* adst1 = asrc1 + 160000;            // 40000*4
    ushort* agg1b = (ushort*)(adst1 + 160000); // 40000*128 bf16
    // after gather1, h1b region is dead -> layer-2 buffers overlay it
    ushort* h2b  = (ushort*)h1b;              // 40000*32 bf16
    float* asrc2 = (float*)(h2b + 1280000);   // 40000
    float* adst2 = asrc2 + 40000;             // 40000
    ushort* agg2b = (ushort*)(adst2 + 40000); // 40000*32 bf16

    // cnt=1 init + W1/W2/W_out fragment packs
    prep_kernel<<<52, 256, 0, stream>>>(W1, W2, W_out, (int4*)cnt, Wf, Wf2, Wfo);

    // Layer-1 GEMM (MFMA) ∥ histogram-with-rank
    gemm1_hist_kernel<<<G1_BLOCKS + HIST_BLOCKS, 256, 0, stream>>>(
        x, Wf, a_src1, a_dst1, h1b, asrc1, adst1, eidx, cnt, rank);

    // CSR scan
    scanA_kernel<<<SCAN_BLOCKS, 256, 0, stream>>>(cnt, rowptr, bsum);
    scanB_kernel<<<1, 256, 0, stream>>>(bsum);

    // Atomic-free bucket fill
    fill_kernel<<<(E_TOT + 255) / 256, 256, 0, stream>>>(
        eidx, rowptr, bsum, rank, esrc);

    // Layer 1 aggregate (bf16 out)
    gather1_kernel<<<5000, 256, 0, stream>>>(rowptr, bsum, esrc, asrc1, adst1,
                                             h1b, b1, agg1b);

    // Layer 2 (MFMA GEMM + gather)
    gemm2_kernel<<<625, 256, 0, stream>>>(agg1b, Wf2, a_src2, a_dst2,
                                          h2b, asrc2, adst2);
    gather2_kernel<<<5000, 256, 0, stream>>>(rowptr, bsum, esrc, asrc2, adst2,
                                             h2b, b2, agg2b);

    // Output projection (MFMA)
    out_gemm_kernel<<<625, 256, 0, stream>>>(agg2b, Wfo, b_out, out);
}

// Round 22
// 113.991 us; speedup vs baseline: 1.2311x; 1.0451x over previous
//
#include <hip/hip_runtime.h>

#define N_NODES 40000
#define E_EDGES 640000
#define E_TOT   (E_EDGES + N_NODES)
#define SCAN_BLOCKS ((N_NODES + 255) / 256)   // 157
#define G1_BLOCKS 625                         // 64 rows per block (4 waves x 16)
#define HIST_BLOCKS ((E_EDGES + 255) / 256)   // 2500

typedef unsigned int uint;
typedef unsigned short ushort;
typedef __attribute__((ext_vector_type(8))) short short8v;   // 8 bf16 (4 VGPRs)
typedef __attribute__((ext_vector_type(4))) float f32x4;     // MFMA accumulator

// bf16 helpers (RNE pack, cheap unpack)
__device__ __forceinline__ ushort f2bf(float f) {
    uint u = __float_as_uint(f);
    u += 0x7FFFu + ((u >> 16) & 1u);
    return (ushort)(u >> 16);
}
__device__ __forceinline__ uint pk_bf(float lo, float hi) {
    return (uint)f2bf(lo) | ((uint)f2bf(hi) << 16);
}
__device__ __forceinline__ float bf_lo(uint w) { return __uint_as_float(w << 16); }
__device__ __forceinline__ float bf_hi(uint w) { return __uint_as_float(w & 0xFFFF0000u); }
__device__ __forceinline__ float bf2f(ushort v) { return __uint_as_float((uint)v << 16); }

// ===========================================================================
// prep: blocks 0..39  -> cnt[i] = 1 (self-loop baked in -> occupies rank 0)
//       blocks 40..47 -> pack W1 (128x128) into MFMA B-fragment order
//       blocks 48..49 -> pack W2 (128x32), 2 column tiles x 4 K-steps
//       blocks 50..51 -> pack W_out (32x112), 7 column tiles x 1 K-step
// ===========================================================================
__global__ __launch_bounds__(256) void prep_kernel(
    const float* __restrict__ W1, const float* __restrict__ W2,
    const float* __restrict__ W_out,
    int4* __restrict__ cnt4, ushort* __restrict__ Wf,
    ushort* __restrict__ Wf2, ushort* __restrict__ Wfo)
{
    if (blockIdx.x < 40) {
        const int i = blockIdx.x * 256 + threadIdx.x;
        if (i < 40064 / 4) cnt4[i] = make_int4(1, 1, 1, 1);
        return;
    }
    if (blockIdx.x < 48) {
        const int s = (blockIdx.x - 40) * 256 + threadIdx.x;   // 0..2047
        const int kk = s >> 9;
        const int rem = s & 511;
        const int ct = rem >> 6;
        const int l = rem & 63;
        const int k0 = kk * 32 + (l >> 4) * 8;
        const int col = ct * 16 + (l & 15);
        uint4 o;
        o.x = pk_bf(W1[(k0 + 0) * 128 + col], W1[(k0 + 1) * 128 + col]);
        o.y = pk_bf(W1[(k0 + 2) * 128 + col], W1[(k0 + 3) * 128 + col]);
        o.z = pk_bf(W1[(k0 + 4) * 128 + col], W1[(k0 + 5) * 128 + col]);
        o.w = pk_bf(W1[(k0 + 6) * 128 + col], W1[(k0 + 7) * 128 + col]);
        ((uint4*)Wf)[s] = o;
        return;
    }
    if (blockIdx.x < 50) {
        const int s = (blockIdx.x - 48) * 256 + threadIdx.x;   // 0..511
        const int kk = s >> 7;
        const int rem = s & 127;
        const int ct = rem >> 6;
        const int l = rem & 63;
        const int k0 = kk * 32 + (l >> 4) * 8;
        const int col = ct * 16 + (l & 15);
        uint4 o;
        o.x = pk_bf(W2[(k0 + 0) * 32 + col], W2[(k0 + 1) * 32 + col]);
        o.y = pk_bf(W2[(k0 + 2) * 32 + col], W2[(k0 + 3) * 32 + col]);
        o.z = pk_bf(W2[(k0 + 4) * 32 + col], W2[(k0 + 5) * 32 + col]);
        o.w = pk_bf(W2[(k0 + 6) * 32 + col], W2[(k0 + 7) * 32 + col]);
        ((uint4*)Wf2)[s] = o;
        return;
    }
    {
        const int s = (blockIdx.x - 50) * 256 + threadIdx.x;   // 0..511, valid <448
        if (s >= 448) return;
        const int ct = s >> 6;
        const int l = s & 63;
        const int k0 = (l >> 4) * 8;
        const int col = ct * 16 + (l & 15);
        uint4 o;
        o.x = pk_bf(W_out[(k0 + 0) * 112 + col], W_out[(k0 + 1) * 112 + col]);
        o.y = pk_bf(W_out[(k0 + 2) * 112 + col], W_out[(k0 + 3) * 112 + col]);
        o.z = pk_bf(W_out[(k0 + 4) * 112 + col], W_out[(k0 + 5) * 112 + col]);
        o.w = pk_bf(W_out[(k0 + 6) * 112 + col], W_out[(k0 + 7) * 112 + col]);
        ((uint4*)Wfo)[s] = o;
    }
}

// ===========================================================================
// FUSED gemm1 (MFMA) ∥ hist+rank (block-range partition, independent).
// ===========================================================================
__global__ __launch_bounds__(256) void gemm1_hist_kernel(
    const float* __restrict__ x, const ushort* __restrict__ Wf,
    const float* __restrict__ a_src, const float* __restrict__ a_dst,
    ushort* __restrict__ h1b, float* __restrict__ asrc, float* __restrict__ adst,
    const int* __restrict__ eidx, int* __restrict__ cnt, int* __restrict__ rank)
{
    if (blockIdx.x >= G1_BLOCKS) {
        const int e = (blockIdx.x - G1_BLOCKS) * 256 + threadIdx.x;
        if (e < E_EDGES)
            rank[e] = atomicAdd(&cnt[eidx[E_EDGES + e]], 1);
        return;
    }

    const int wv = threadIdx.x >> 6;
    const int lane = threadIdx.x & 63;
    const int rowbase = blockIdx.x * 64 + wv * 16;
    const int arow = rowbase + (lane & 15);
    const int kof = (lane >> 4) * 8;

    f32x4 acc0 = {0.f,0.f,0.f,0.f}, acc1 = {0.f,0.f,0.f,0.f};
    f32x4 acc2 = {0.f,0.f,0.f,0.f}, acc3 = {0.f,0.f,0.f,0.f};
    f32x4 acc4 = {0.f,0.f,0.f,0.f}, acc5 = {0.f,0.f,0.f,0.f};
    f32x4 acc6 = {0.f,0.f,0.f,0.f}, acc7 = {0.f,0.f,0.f,0.f};

    const short8v* WfV = (const short8v*)Wf;
#pragma unroll
    for (int kk = 0; kk < 4; ++kk) {
        const float* ap = &x[(size_t)arow * 128 + kk * 32 + kof];
        const float4 a0 = *(const float4*)ap;
        const float4 a1 = *(const float4*)(ap + 4);
        short8v af;
        af[0] = (short)f2bf(a0.x); af[1] = (short)f2bf(a0.y);
        af[2] = (short)f2bf(a0.z); af[3] = (short)f2bf(a0.w);
        af[4] = (short)f2bf(a1.x); af[5] = (short)f2bf(a1.y);
        af[6] = (short)f2bf(a1.z); af[7] = (short)f2bf(a1.w);
        const int base = kk * 8 * 64 + lane;
        acc0 = __builtin_amdgcn_mfma_f32_16x16x32_bf16(af, WfV[base + 0 * 64], acc0, 0, 0, 0);
        acc1 = __builtin_amdgcn_mfma_f32_16x16x32_bf16(af, WfV[base + 1 * 64], acc1, 0, 0, 0);
        acc2 = __builtin_amdgcn_mfma_f32_16x16x32_bf16(af, WfV[base + 2 * 64], acc2, 0, 0, 0);
        acc3 = __builtin_amdgcn_mfma_f32_16x16x32_bf16(af, WfV[base + 3 * 64], acc3, 0, 0, 0);
        acc4 = __builtin_amdgcn_mfma_f32_16x16x32_bf16(af, WfV[base + 4 * 64], acc4, 0, 0, 0);
        acc5 = __builtin_amdgcn_mfma_f32_16x16x32_bf16(af, WfV[base + 5 * 64], acc5, 0, 0, 0);
        acc6 = __builtin_amdgcn_mfma_f32_16x16x32_bf16(af, WfV[base + 6 * 64], acc6, 0, 0, 0);
        acc7 = __builtin_amdgcn_mfma_f32_16x16x32_bf16(af, WfV[base + 7 * 64], acc7, 0, 0, 0);
    }

    const int cl = lane & 15;
    const int rg = lane >> 4;
    float csA[8], cdA[8];
#pragma unroll
    for (int ct = 0; ct < 8; ++ct) {
        csA[ct] = a_src[(ct >> 1) * 32 + (ct & 1) * 16 + cl];
        cdA[ct] = a_dst[(ct >> 1) * 32 + (ct & 1) * 16 + cl];
    }
    const f32x4 accv[8] = { acc0, acc1, acc2, acc3, acc4, acc5, acc6, acc7 };
#pragma unroll
    for (int r = 0; r < 4; ++r) {
        const int n = rowbase + rg * 4 + r;
        ushort* hrow = &h1b[(size_t)n * 128 + cl];
#pragma unroll
        for (int ct = 0; ct < 8; ++ct) hrow[ct * 16] = f2bf(accv[ct][r]);
#pragma unroll
        for (int h = 0; h < 4; ++h) {
            float ps = accv[2 * h][r] * csA[2 * h] + accv[2 * h + 1][r] * csA[2 * h + 1];
            float pd = accv[2 * h][r] * cdA[2 * h] + accv[2 * h + 1][r] * cdA[2 * h + 1];
            ps += __shfl_xor(ps, 1); ps += __shfl_xor(ps, 2);
            ps += __shfl_xor(ps, 4); ps += __shfl_xor(ps, 8);
            pd += __shfl_xor(pd, 1); pd += __shfl_xor(pd, 2);
            pd += __shfl_xor(pd, 4); pd += __shfl_xor(pd, 8);
            if (cl == 0) { asrc[n * 4 + h] = ps; adst[n * 4 + h] = pd; }
        }
    }
}

// ===========================================================================
// scanA / scanB (split, battle-tested).
// ===========================================================================
__global__ __launch_bounds__(256) void scanA_kernel(
    const int* __restrict__ cnt, int* __restrict__ rowptr, int* __restrict__ bsum)
{
    const int i = blockIdx.x * 256 + threadIdx.x;
    const int lane = threadIdx.x & 63;
    const int wave = threadIdx.x >> 6;
    const int v = (i < N_NODES) ? cnt[i] : 0;
    int incl = v;
#pragma unroll
    for (int off = 1; off < 64; off <<= 1) {
        int u = __shfl_up(incl, off);
        if (lane >= off) incl += u;
    }
    __shared__ int ws[4];
    if (lane == 63) ws[wave] = incl;
    __syncthreads();
    int woff = 0;
    if (wave > 0) woff += ws[0];
    if (wave > 1) woff += ws[1];
    if (wave > 2) woff += ws[2];
    if (i <= N_NODES) rowptr[i] = woff + incl - v;
    if (threadIdx.x == 255) bsum[blockIdx.x] = woff + incl;
}

__global__ __launch_bounds__(256) void scanB_kernel(int* __restrict__ bsum)
{
    const int t = threadIdx.x;
    const int lane = t & 63;
    const int wave = t >> 6;
    const int v = (t < SCAN_BLOCKS) ? bsum[t] : 0;
    int incl = v;
#pragma unroll
    for (int off = 1; off < 64; off <<= 1) {
        int u = __shfl_up(incl, off);
        if (lane >= off) incl += u;
    }
    __shared__ int ws[4];
    if (lane == 63) ws[wave] = incl;
    __syncthreads();
    int woff = 0;
    if (wave > 0) woff += ws[0];
    if (wave > 1) woff += ws[1];
    if (wave > 2) woff += ws[2];
    if (t < SCAN_BLOCKS) bsum[t] = woff + incl - v;
}

// ===========================================================================
// fill (ATOMIC-FREE): esrc[rowptr[d] + bsum[d>>8] + rank[e]] = s.
// ===========================================================================
__global__ __launch_bounds__(256) void fill_kernel(
    const int* __restrict__ eidx, const int* __restrict__ rowptr,
    const int* __restrict__ bsum, const int* __restrict__ rank,
    int* __restrict__ esrc)
{
    const int e = blockIdx.x * 256 + threadIdx.x;
    if (e >= E_TOT) return;
    int s, d, r;
    if (e < E_EDGES) { s = eidx[e]; d = eidx[E_EDGES + e]; r = rank[e]; }
    else             { s = d = e - E_EDGES; r = 0; }
    esrc[rowptr[d] + bsum[d >> 8] + r] = s;
}

// ===========================================================================
// Gather pass 1: 32 lanes per dst node (2 nodes/wave); bf16 rows; pipelined
// 8-deep main + 4-deep mid-tail + scalar tail (avg scalar edges 3.5 -> 1.5);
// fused norm + bias + ELU; agg1 stored bf16 (feeds MFMA gemm2).
// ===========================================================================
__global__ __launch_bounds__(256) void gather1_kernel(
    const int* __restrict__ rowptr, const int* __restrict__ bsum,
    const int* __restrict__ esrc, const float* __restrict__ asrc,
    const float* __restrict__ adst,
    const ushort* __restrict__ h1b, const float* __restrict__ b,
    ushort* __restrict__ agg1b)
{
    const int t = blockIdx.x * 256 + threadIdx.x;
    const int node = t >> 5;                 // grid exact: 5000*256/32 = 40000
    const int l32 = t & 31;
    const int head = l32 >> 3;
    const int cb = l32 * 4;
    const float ad = adst[node * 4 + head];
    const int beg = rowptr[node] + bsum[node >> 8];
    const int end = rowptr[node + 1] + bsum[(node + 1) >> 8];
    float acc0 = 0.f, acc1 = 0.f, acc2 = 0.f, acc3 = 0.f, den = 0.f;

    int i = beg;
    for (; i + 8 <= end; i += 8) {
        int s[8];
        float a[8];
        uint2 w[8];
#pragma unroll
        for (int j = 0; j < 8; ++j) s[j] = esrc[i + j];
#pragma unroll
        for (int j = 0; j < 8; ++j) a[j] = asrc[s[j] * 4 + head];
#pragma unroll
        for (int j = 0; j < 8; ++j)
            w[j] = *(const uint2*)&h1b[(size_t)s[j] * 128 + cb];
#pragma unroll
        for (int j = 0; j < 8; ++j) {
            float v = a[j] + ad; v = v > 0.f ? v : 0.2f * v;
            const float e = __expf(v);
            den += e;
            acc0 = fmaf(e, bf_lo(w[j].x), acc0);
            acc1 = fmaf(e, bf_hi(w[j].x), acc1);
            acc2 = fmaf(e, bf_lo(w[j].y), acc2);
            acc3 = fmaf(e, bf_hi(w[j].y), acc3);
        }
    }
    for (; i + 4 <= end; i += 4) {   // 4-deep mid-tail
        int s[4];
        float a[4];
        uint2 w[4];
#pragma unroll
        for (int j = 0; j < 4; ++j) s[j] = esrc[i + j];
#pragma unroll
        for (int j = 0; j < 4; ++j) a[j] = asrc[s[j] * 4 + head];
#pragma unroll
        for (int j = 0; j < 4; ++j)
            w[j] = *(const uint2*)&h1b[(size_t)s[j] * 128 + cb];
#pragma unroll
        for (int j = 0; j < 4; ++j) {
            float v = a[j] + ad; v = v > 0.f ? v : 0.2f * v;
            const float e = __expf(v);
            den += e;
            acc0 = fmaf(e, bf_lo(w[j].x), acc0);
            acc1 = fmaf(e, bf_hi(w[j].x), acc1);
            acc2 = fmaf(e, bf_lo(w[j].y), acc2);
            acc3 = fmaf(e, bf_hi(w[j].y), acc3);
        }
    }
    for (; i < end; ++i) {
        const int s = esrc[i];
        float av = asrc[s * 4 + head] + ad;
        av = av > 0.f ? av : 0.2f * av;
        const float ex = __expf(av);
        const uint2 w = *(const uint2*)&h1b[(size_t)s * 128 + cb];
        den += ex;
        acc0 = fmaf(ex, bf_lo(w.x), acc0);
        acc1 = fmaf(ex, bf_hi(w.x), acc1);
        acc2 = fmaf(ex, bf_lo(w.y), acc2);
        acc3 = fmaf(ex, bf_hi(w.y), acc3);
    }

    const float inv = 1.f / (den + 1e-16f);
    const float4 bv = *(const float4*)&b[cb];
    float o0 = acc0 * inv + bv.x;
    float o1 = acc1 * inv + bv.y;
    float o2 = acc2 * inv + bv.z;
    float o3 = acc3 * inv + bv.w;
    o0 = o0 > 0.f ? o0 : expm1f(o0);
    o1 = o1 > 0.f ? o1 : expm1f(o1);
    o2 = o2 > 0.f ? o2 : expm1f(o2);
    o3 = o3 > 0.f ? o3 : expm1f(o3);
    uint2 o;
    o.x = pk_bf(o0, o1);
    o.y = pk_bf(o2, o3);
    *(uint2*)&agg1b[(size_t)node * 128 + cb] = o;
}

// ===========================================================================
// GEMM2 (MFMA): h2 = agg1 @ W2  [40000x128 @ 128x32], bf16 in, f32 accum.
// ===========================================================================
__global__ __launch_bounds__(256) void gemm2_kernel(
    const ushort* __restrict__ agg1b, const ushort* __restrict__ Wf2,
    const float* __restrict__ a_src, const float* __restrict__ a_dst,
    ushort* __restrict__ h2b, float* __restrict__ asrc, float* __restrict__ adst)
{
    const int wv = threadIdx.x >> 6;
    const int lane = threadIdx.x & 63;
    const int rowbase = blockIdx.x * 64 + wv * 16;
    const int arow = rowbase + (lane & 15);
    const int kof = (lane >> 4) * 8;

    f32x4 acc0 = {0.f,0.f,0.f,0.f}, acc1 = {0.f,0.f,0.f,0.f};
    const short8v* Wf2V = (const short8v*)Wf2;
#pragma unroll
    for (int kk = 0; kk < 4; ++kk) {
        const short8v af = *(const short8v*)&agg1b[(size_t)arow * 128 + kk * 32 + kof];
        const int base = kk * 2 * 64 + lane;
        acc0 = __builtin_amdgcn_mfma_f32_16x16x32_bf16(af, Wf2V[base], acc0, 0, 0, 0);
        acc1 = __builtin_amdgcn_mfma_f32_16x16x32_bf16(af, Wf2V[base + 64], acc1, 0, 0, 0);
    }

    const int cl = lane & 15;
    const int rg = lane >> 4;
    const float cs0 = a_src[cl], cs1 = a_src[16 + cl];
    const float cd0 = a_dst[cl], cd1 = a_dst[16 + cl];
#pragma unroll
    for (int r = 0; r < 4; ++r) {
        const int n = rowbase + rg * 4 + r;
        h2b[(size_t)n * 32 + cl]      = f2bf(acc0[r]);
        h2b[(size_t)n * 32 + 16 + cl] = f2bf(acc1[r]);
        float ps = acc0[r] * cs0 + acc1[r] * cs1;
        float pd = acc0[r] * cd0 + acc1[r] * cd1;
        ps += __shfl_xor(ps, 1); ps += __shfl_xor(ps, 2);
        ps += __shfl_xor(ps, 4); ps += __shfl_xor(ps, 8);
        pd += __shfl_xor(pd, 1); pd += __shfl_xor(pd, 2);
        pd += __shfl_xor(pd, 4); pd += __shfl_xor(pd, 8);
        if (cl == 0) { asrc[n] = ps; adst[n] = pd; }
    }
}

// ===========================================================================
// Gather pass 2: 32 lanes per dst node, bf16 h2 rows; 8-deep + 4-deep tail;
// fused norm + bias + ELU; agg2 stored bf16 (feeds MFMA out_gemm).
// ===========================================================================
__global__ __launch_bounds__(256) void gather2_kernel(
    const int* __restrict__ rowptr, const int* __restrict__ bsum,
    const int* __restrict__ esrc,
    const float* __restrict__ asrc, const float* __restrict__ adst,
    const ushort* __restrict__ h2b, const float* __restrict__ b,
    ushort* __restrict__ agg2b)
{
    const int t = blockIdx.x * 256 + threadIdx.x;
    const int node = t >> 5;
    const int c = t & 31;
    if (node >= N_NODES) return;
    const float ad = adst[node];
    const int beg = rowptr[node] + bsum[node >> 8];
    const int end = rowptr[node + 1] + bsum[(node + 1) >> 8];
    float acc = 0.f, den = 0.f;

    int i = beg;
    for (; i + 8 <= end; i += 8) {
        int s[8];
        float a[8];
        ushort w[8];
#pragma unroll
        for (int j = 0; j < 8; ++j) s[j] = esrc[i + j];
#pragma unroll
        for (int j = 0; j < 8; ++j) a[j] = asrc[s[j]];
#pragma unroll
        for (int j = 0; j < 8; ++j) w[j] = h2b[(size_t)s[j] * 32 + c];
#pragma unroll
        for (int j = 0; j < 8; ++j) {
            float v = a[j] + ad; v = v > 0.f ? v : 0.2f * v;
            const float e = __expf(v);
            den += e;
            acc = fmaf(e, bf2f(w[j]), acc);
        }
    }
    for (; i + 4 <= end; i += 4) {   // 4-deep mid-tail
        int s[4];
        float a[4];
        ushort w[4];
#pragma unroll
        for (int j = 0; j < 4; ++j) s[j] = esrc[i + j];
#pragma unroll
        for (int j = 0; j < 4; ++j) a[j] = asrc[s[j]];
#pragma unroll
        for (int j = 0; j < 4; ++j) w[j] = h2b[(size_t)s[j] * 32 + c];
#pragma unroll
        for (int j = 0; j < 4; ++j) {
            float v = a[j] + ad; v = v > 0.f ? v : 0.2f * v;
            const float e = __expf(v);
            den += e;
            acc = fmaf(e, bf2f(w[j]), acc);
        }
    }
    for (; i < end; ++i) {
        const int s = esrc[i];
        float av = asrc[s] + ad;
        av = av > 0.f ? av : 0.2f * av;
        const float ex = __expf(av);
        den += ex;
        acc = fmaf(ex, bf2f(h2b[(size_t)s * 32 + c]), acc);
    }

    const float inv = 1.f / (den + 1e-16f);
    float o = acc * inv + b[c];
    o = o > 0.f ? o : expm1f(o);
    agg2b[(size_t)node * 32 + c] = f2bf(o);
}

// ===========================================================================
// Output GEMM (MFMA): out = agg2 @ W_out + b_out  [40000x32 @ 32x112].
// ===========================================================================
__global__ __launch_bounds__(256) void out_gemm_kernel(
    const ushort* __restrict__ agg2b, const ushort* __restrict__ Wfo,
    const float* __restrict__ b_out, float* __restrict__ out)
{
    const int wv = threadIdx.x >> 6;
    const int lane = threadIdx.x & 63;
    const int rowbase = blockIdx.x * 64 + wv * 16;
    const int arow = rowbase + (lane & 15);
    const int kof = (lane >> 4) * 8;

    const short8v af = *(const short8v*)&agg2b[(size_t)arow * 32 + kof];
    const short8v* WfoV = (const short8v*)Wfo;
    f32x4 acc[7];
#pragma unroll
    for (int ct = 0; ct < 7; ++ct) {
        f32x4 z = {0.f, 0.f, 0.f, 0.f};
        acc[ct] = __builtin_amdgcn_mfma_f32_16x16x32_bf16(af, WfoV[ct * 64 + lane], z, 0, 0, 0);
    }

    const int cl = lane & 15;
    const int rg = lane >> 4;
    float bo[7];
#pragma unroll
    for (int ct = 0; ct < 7; ++ct) bo[ct] = b_out[ct * 16 + cl];
#pragma unroll
    for (int r = 0; r < 4; ++r) {
        const int n = rowbase + rg * 4 + r;
        float* orow = &out[(size_t)n * 112 + cl];
#pragma unroll
        for (int ct = 0; ct < 7; ++ct) orow[ct * 16] = acc[ct][r] + bo[ct];
    }
}

// ===========================================================================
extern "C" void kernel_launch(void* const* d_in, const int* in_sizes, int n_in,
                              void* d_out, int out_size, void* d_ws, size_t ws_size,
                              hipStream_t stream) {
    const float* x      = (const float*)d_in[0];
    const int*   eidx   = (const int*)d_in[1];
    const float* W1     = (const float*)d_in[2];
    const float* a_src1 = (const float*)d_in[3];
    const float* a_dst1 = (const float*)d_in[4];
    const float* b1     = (const float*)d_in[5];
    const float* W2     = (const float*)d_in[6];
    const float* a_src2 = (const float*)d_in[7];
    const float* a_dst2 = (const float*)d_in[8];
    const float* b2     = (const float*)d_in[9];
    const float* W_out  = (const float*)d_in[10];
    const float* b_out  = (const float*)d_in[11];
    float* out = (float*)d_out;

    // ---- workspace layout (~30 MB) ----
    int* rowptr = (int*)d_ws;                 // 40064 (uses [0..40000])
    int* cnt    = rowptr + 40064;             // 40064 histogram (init = 1)
    int* bsum   = cnt + 40064;                // 192 block sums (exclusive)
    int* rank   = bsum + 192;                 // 680000 per-edge bucket rank
    ushort* Wf  = (ushort*)(rank + 680000);   // 16384 bf16 (W1 fragments)
    ushort* Wf2 = Wf + 16384;                 // 4096 bf16 (W2 fragments)
    ushort* Wfo = Wf2 + 4096;                 // 3584 bf16 (+pad 512) W_out fragments
    int* esrc   = (int*)(Wfo + 4096);         // 680000 CSR edge sources
    ushort* h1b  = (ushort*)(esrc + 680000);  // 40000*128 bf16
    float* asrc1 = (float*)(h1b + 5120000);   // 40000*4
    float* adst1 = asrc1 + 160000;            // 40000*4
    ushort* agg1b = (ushort*)(adst1 + 160000); // 40000*128 bf16
    // after gather1, h1b region is dead -> layer-2 buffers overlay it
    ushort* h2b  = (ushort*)h1b;              // 40000*32 bf16
    float* asrc2 = (float*)(h2b + 1280000);   // 40000
    float* adst2 = asrc2 + 40000;             // 40000
    ushort* agg2b = (ushort*)(adst2 + 40000); // 40000*32 bf16

    // cnt=1 init + W1/W2/W_out fragment packs
    prep_kernel<<<52, 256, 0, stream>>>(W1, W2, W_out, (int4*)cnt, Wf, Wf2, Wfo);

    // Layer-1 GEMM (MFMA) ∥ histogram-with-rank
    gemm1_hist_kernel<<<G1_BLOCKS + HIST_BLOCKS, 256, 0, stream>>>(
        x, Wf, a_src1, a_dst1, h1b, asrc1, adst1, eidx, cnt, rank);

    // CSR scan
    scanA_kernel<<<SCAN_BLOCKS, 256, 0, stream>>>(cnt, rowptr, bsum);
    scanB_kernel<<<1, 256, 0, stream>>>(bsum);

    // Atomic-free bucket fill
    fill_kernel<<<(E_TOT + 255) / 256, 256, 0, stream>>>(
        eidx, rowptr, bsum, rank, esrc);

    // Layer 1 aggregate (bf16 out)
    gather1_kernel<<<5000, 256, 0, stream>>>(rowptr, bsum, esrc, asrc1, adst1,
                                             h1b, b1, agg1b);

    // Layer 2 (MFMA GEMM + gather)
    gemm2_kernel<<<625, 256, 0, stream>>>(agg1b, Wf2, a_src2, a_dst2,
                                          h2b, asrc2, adst2);
    gather2_kernel<<<5000, 256, 0, stream>>>(rowptr, bsum, esrc, asrc2, adst2,
                                             h2b, b2, agg2b);

    // Output projection (MFMA)
    out_gemm_kernel<<<625, 256, 0, stream>>>(agg2b, Wfo, b_out, out);
}

// Round 23
// 110.458 us; speedup vs baseline: 1.2705x; 1.0320x over previous
//
#include <hip/hip_runtime.h>

#define N_NODES 40000
#define E_EDGES 640000
#define E_TOT   (E_EDGES + N_NODES)
#define SCAN_BLOCKS ((N_NODES + 255) / 256)   // 157
#define G1_BLOCKS 625                         // 64 rows per block (4 waves x 16)
#define HIST_BLOCKS ((E_EDGES + 255) / 256)   // 2500

typedef unsigned int uint;
typedef unsigned short ushort;
typedef __attribute__((ext_vector_type(8))) short short8v;   // 8 bf16 (4 VGPRs)
typedef __attribute__((ext_vector_type(4))) float f32x4;     // MFMA accumulator

// bf16 helpers (RNE pack, cheap unpack)
__device__ __forceinline__ ushort f2bf(float f) {
    uint u = __float_as_uint(f);
    u += 0x7FFFu + ((u >> 16) & 1u);
    return (ushort)(u >> 16);
}
__device__ __forceinline__ uint pk_bf(float lo, float hi) {
    return (uint)f2bf(lo) | ((uint)f2bf(hi) << 16);
}
__device__ __forceinline__ float bf_lo(uint w) { return __uint_as_float(w << 16); }
__device__ __forceinline__ float bf_hi(uint w) { return __uint_as_float(w & 0xFFFF0000u); }
__device__ __forceinline__ float bf2f(ushort v) { return __uint_as_float((uint)v << 16); }

// ===========================================================================
// prep: blocks 0..39  -> cnt[i] = 1 (self-loop baked in -> occupies rank 0)
//       blocks 40..47 -> pack W1 (128x128) into MFMA B-fragment order
//       blocks 48..49 -> pack W2 (128x32), 2 column tiles x 4 K-steps
//       blocks 50..51 -> pack W_out (32x112), 7 column tiles x 1 K-step
// ===========================================================================
__global__ __launch_bounds__(256) void prep_kernel(
    const float* __restrict__ W1, const float* __restrict__ W2,
    const float* __restrict__ W_out,
    int4* __restrict__ cnt4, ushort* __restrict__ Wf,
    ushort* __restrict__ Wf2, ushort* __restrict__ Wfo)
{
    if (blockIdx.x < 40) {
        const int i = blockIdx.x * 256 + threadIdx.x;
        if (i < 40064 / 4) cnt4[i] = make_int4(1, 1, 1, 1);
        return;
    }
    if (blockIdx.x < 48) {
        const int s = (blockIdx.x - 40) * 256 + threadIdx.x;   // 0..2047
        const int kk = s >> 9;
        const int rem = s & 511;
        const int ct = rem >> 6;
        const int l = rem & 63;
        const int k0 = kk * 32 + (l >> 4) * 8;
        const int col = ct * 16 + (l & 15);
        uint4 o;
        o.x = pk_bf(W1[(k0 + 0) * 128 + col], W1[(k0 + 1) * 128 + col]);
        o.y = pk_bf(W1[(k0 + 2) * 128 + col], W1[(k0 + 3) * 128 + col]);
        o.z = pk_bf(W1[(k0 + 4) * 128 + col], W1[(k0 + 5) * 128 + col]);
        o.w = pk_bf(W1[(k0 + 6) * 128 + col], W1[(k0 + 7) * 128 + col]);
        ((uint4*)Wf)[s] = o;
        return;
    }
    if (blockIdx.x < 50) {
        const int s = (blockIdx.x - 48) * 256 + threadIdx.x;   // 0..511
        const int kk = s >> 7;
        const int rem = s & 127;
        const int ct = rem >> 6;
        const int l = rem & 63;
        const int k0 = kk * 32 + (l >> 4) * 8;
        const int col = ct * 16 + (l & 15);
        uint4 o;
        o.x = pk_bf(W2[(k0 + 0) * 32 + col], W2[(k0 + 1) * 32 + col]);
        o.y = pk_bf(W2[(k0 + 2) * 32 + col], W2[(k0 + 3) * 32 + col]);
        o.z = pk_bf(W2[(k0 + 4) * 32 + col], W2[(k0 + 5) * 32 + col]);
        o.w = pk_bf(W2[(k0 + 6) * 32 + col], W2[(k0 + 7) * 32 + col]);
        ((uint4*)Wf2)[s] = o;
        return;
    }
    {
        const int s = (blockIdx.x - 50) * 256 + threadIdx.x;   // 0..511, valid <448
        if (s >= 448) return;
        const int ct = s >> 6;
        const int l = s & 63;
        const int k0 = (l >> 4) * 8;
        const int col = ct * 16 + (l & 15);
        uint4 o;
        o.x = pk_bf(W_out[(k0 + 0) * 112 + col], W_out[(k0 + 1) * 112 + col]);
        o.y = pk_bf(W_out[(k0 + 2) * 112 + col], W_out[(k0 + 3) * 112 + col]);
        o.z = pk_bf(W_out[(k0 + 4) * 112 + col], W_out[(k0 + 5) * 112 + col]);
        o.w = pk_bf(W_out[(k0 + 6) * 112 + col], W_out[(k0 + 7) * 112 + col]);
        ((uint4*)Wfo)[s] = o;
    }
}

// ===========================================================================
// FUSED gemm1 (MFMA) ∥ hist+rank (block-range partition, independent).
// rank stored as ushort (max bucket rank ~= max in-degree << 65536).
// ===========================================================================
__global__ __launch_bounds__(256) void gemm1_hist_kernel(
    const float* __restrict__ x, const ushort* __restrict__ Wf,
    const float* __restrict__ a_src, const float* __restrict__ a_dst,
    ushort* __restrict__ h1b, float* __restrict__ asrc, float* __restrict__ adst,
    const int* __restrict__ eidx, int* __restrict__ cnt, ushort* __restrict__ rank)
{
    if (blockIdx.x >= G1_BLOCKS) {
        const int e = (blockIdx.x - G1_BLOCKS) * 256 + threadIdx.x;
        if (e < E_EDGES)
            rank[e] = (ushort)atomicAdd(&cnt[eidx[E_EDGES + e]], 1);
        return;
    }

    const int wv = threadIdx.x >> 6;
    const int lane = threadIdx.x & 63;
    const int rowbase = blockIdx.x * 64 + wv * 16;
    const int arow = rowbase + (lane & 15);
    const int kof = (lane >> 4) * 8;

    f32x4 acc0 = {0.f,0.f,0.f,0.f}, acc1 = {0.f,0.f,0.f,0.f};
    f32x4 acc2 = {0.f,0.f,0.f,0.f}, acc3 = {0.f,0.f,0.f,0.f};
    f32x4 acc4 = {0.f,0.f,0.f,0.f}, acc5 = {0.f,0.f,0.f,0.f};
    f32x4 acc6 = {0.f,0.f,0.f,0.f}, acc7 = {0.f,0.f,0.f,0.f};

    const short8v* WfV = (const short8v*)Wf;
#pragma unroll
    for (int kk = 0; kk < 4; ++kk) {
        const float* ap = &x[(size_t)arow * 128 + kk * 32 + kof];
        const float4 a0 = *(const float4*)ap;
        const float4 a1 = *(const float4*)(ap + 4);
        short8v af;
        af[0] = (short)f2bf(a0.x); af[1] = (short)f2bf(a0.y);
        af[2] = (short)f2bf(a0.z); af[3] = (short)f2bf(a0.w);
        af[4] = (short)f2bf(a1.x); af[5] = (short)f2bf(a1.y);
        af[6] = (short)f2bf(a1.z); af[7] = (short)f2bf(a1.w);
        const int base = kk * 8 * 64 + lane;
        acc0 = __builtin_amdgcn_mfma_f32_16x16x32_bf16(af, WfV[base + 0 * 64], acc0, 0, 0, 0);
        acc1 = __builtin_amdgcn_mfma_f32_16x16x32_bf16(af, WfV[base + 1 * 64], acc1, 0, 0, 0);
        acc2 = __builtin_amdgcn_mfma_f32_16x16x32_bf16(af, WfV[base + 2 * 64], acc2, 0, 0, 0);
        acc3 = __builtin_amdgcn_mfma_f32_16x16x32_bf16(af, WfV[base + 3 * 64], acc3, 0, 0, 0);
        acc4 = __builtin_amdgcn_mfma_f32_16x16x32_bf16(af, WfV[base + 4 * 64], acc4, 0, 0, 0);
        acc5 = __builtin_amdgcn_mfma_f32_16x16x32_bf16(af, WfV[base + 5 * 64], acc5, 0, 0, 0);
        acc6 = __builtin_amdgcn_mfma_f32_16x16x32_bf16(af, WfV[base + 6 * 64], acc6, 0, 0, 0);
        acc7 = __builtin_amdgcn_mfma_f32_16x16x32_bf16(af, WfV[base + 7 * 64], acc7, 0, 0, 0);
    }

    const int cl = lane & 15;
    const int rg = lane >> 4;
    float csA[8], cdA[8];
#pragma unroll
    for (int ct = 0; ct < 8; ++ct) {
        csA[ct] = a_src[(ct >> 1) * 32 + (ct & 1) * 16 + cl];
        cdA[ct] = a_dst[(ct >> 1) * 32 + (ct & 1) * 16 + cl];
    }
    const f32x4 accv[8] = { acc0, acc1, acc2, acc3, acc4, acc5, acc6, acc7 };
#pragma unroll
    for (int r = 0; r < 4; ++r) {
        const int n = rowbase + rg * 4 + r;
        ushort* hrow = &h1b[(size_t)n * 128 + cl];
#pragma unroll
        for (int ct = 0; ct < 8; ++ct) hrow[ct * 16] = f2bf(accv[ct][r]);
#pragma unroll
        for (int h = 0; h < 4; ++h) {
            float ps = accv[2 * h][r] * csA[2 * h] + accv[2 * h + 1][r] * csA[2 * h + 1];
            float pd = accv[2 * h][r] * cdA[2 * h] + accv[2 * h + 1][r] * cdA[2 * h + 1];
            ps += __shfl_xor(ps, 1); ps += __shfl_xor(ps, 2);
            ps += __shfl_xor(ps, 4); ps += __shfl_xor(ps, 8);
            pd += __shfl_xor(pd, 1); pd += __shfl_xor(pd, 2);
            pd += __shfl_xor(pd, 4); pd += __shfl_xor(pd, 8);
            if (cl == 0) { asrc[n * 4 + h] = ps; adst[n * 4 + h] = pd; }
        }
    }
}

// ===========================================================================
// scanA / scanB (split, battle-tested).
// ===========================================================================
__global__ __launch_bounds__(256) void scanA_kernel(
    const int* __restrict__ cnt, int* __restrict__ rowptr, int* __restrict__ bsum)
{
    const int i = blockIdx.x * 256 + threadIdx.x;
    const int lane = threadIdx.x & 63;
    const int wave = threadIdx.x >> 6;
    const int v = (i < N_NODES) ? cnt[i] : 0;
    int incl = v;
#pragma unroll
    for (int off = 1; off < 64; off <<= 1) {
        int u = __shfl_up(incl, off);
        if (lane >= off) incl += u;
    }
    __shared__ int ws[4];
    if (lane == 63) ws[wave] = incl;
    __syncthreads();
    int woff = 0;
    if (wave > 0) woff += ws[0];
    if (wave > 1) woff += ws[1];
    if (wave > 2) woff += ws[2];
    if (i <= N_NODES) rowptr[i] = woff + incl - v;
    if (threadIdx.x == 255) bsum[blockIdx.x] = woff + incl;
}

__global__ __launch_bounds__(256) void scanB_kernel(int* __restrict__ bsum)
{
    const int t = threadIdx.x;
    const int lane = t & 63;
    const int wave = t >> 6;
    const int v = (t < SCAN_BLOCKS) ? bsum[t] : 0;
    int incl = v;
#pragma unroll
    for (int off = 1; off < 64; off <<= 1) {
        int u = __shfl_up(incl, off);
        if (lane >= off) incl += u;
    }
    __shared__ int ws[4];
    if (lane == 63) ws[wave] = incl;
    __syncthreads();
    int woff = 0;
    if (wave > 0) woff += ws[0];
    if (wave > 1) woff += ws[1];
    if (wave > 2) woff += ws[2];
    if (t < SCAN_BLOCKS) bsum[t] = woff + incl - v;
}

// ===========================================================================
// fill (ATOMIC-FREE): esrc[rowptr[d] + bsum[d>>8] + rank[e]] = s (ushort).
// ===========================================================================
__global__ __launch_bounds__(256) void fill_kernel(
    const int* __restrict__ eidx, const int* __restrict__ rowptr,
    const int* __restrict__ bsum, const ushort* __restrict__ rank,
    ushort* __restrict__ esrc)
{
    const int e = blockIdx.x * 256 + threadIdx.x;
    if (e >= E_TOT) return;
    int s, d, r;
    if (e < E_EDGES) { s = eidx[e]; d = eidx[E_EDGES + e]; r = rank[e]; }
    else             { s = d = e - E_EDGES; r = 0; }
    esrc[rowptr[d] + bsum[d >> 8] + r] = (ushort)s;
}

// ===========================================================================
// Gather pass 1: 32 lanes per dst node (2 nodes/wave); bf16 rows; pipelined
// 8-deep main + 4-deep mid-tail + scalar tail; ushort esrc stream;
// fused norm + bias + ELU; agg1 stored bf16 (feeds MFMA gemm2).
// ===========================================================================
__global__ __launch_bounds__(256) void gather1_kernel(
    const int* __restrict__ rowptr, const int* __restrict__ bsum,
    const ushort* __restrict__ esrc, const float* __restrict__ asrc,
    const float* __restrict__ adst,
    const ushort* __restrict__ h1b, const float* __restrict__ b,
    ushort* __restrict__ agg1b)
{
    const int t = blockIdx.x * 256 + threadIdx.x;
    const int node = t >> 5;                 // grid exact: 5000*256/32 = 40000
    const int l32 = t & 31;
    const int head = l32 >> 3;
    const int cb = l32 * 4;
    const float ad = adst[node * 4 + head];
    const int beg = rowptr[node] + bsum[node >> 8];
    const int end = rowptr[node + 1] + bsum[(node + 1) >> 8];
    float acc0 = 0.f, acc1 = 0.f, acc2 = 0.f, acc3 = 0.f, den = 0.f;

    int i = beg;
    for (; i + 8 <= end; i += 8) {
        int s[8];
        float a[8];
        uint2 w[8];
#pragma unroll
        for (int j = 0; j < 8; ++j) s[j] = esrc[i + j];
#pragma unroll
        for (int j = 0; j < 8; ++j) a[j] = asrc[s[j] * 4 + head];
#pragma unroll
        for (int j = 0; j < 8; ++j)
            w[j] = *(const uint2*)&h1b[(size_t)s[j] * 128 + cb];
#pragma unroll
        for (int j = 0; j < 8; ++j) {
            float v = a[j] + ad; v = v > 0.f ? v : 0.2f * v;
            const float e = __expf(v);
            den += e;
            acc0 = fmaf(e, bf_lo(w[j].x), acc0);
            acc1 = fmaf(e, bf_hi(w[j].x), acc1);
            acc2 = fmaf(e, bf_lo(w[j].y), acc2);
            acc3 = fmaf(e, bf_hi(w[j].y), acc3);
        }
    }
    for (; i + 4 <= end; i += 4) {   // 4-deep mid-tail
        int s[4];
        float a[4];
        uint2 w[4];
#pragma unroll
        for (int j = 0; j < 4; ++j) s[j] = esrc[i + j];
#pragma unroll
        for (int j = 0; j < 4; ++j) a[j] = asrc[s[j] * 4 + head];
#pragma unroll
        for (int j = 0; j < 4; ++j)
            w[j] = *(const uint2*)&h1b[(size_t)s[j] * 128 + cb];
#pragma unroll
        for (int j = 0; j < 4; ++j) {
            float v = a[j] + ad; v = v > 0.f ? v : 0.2f * v;
            const float e = __expf(v);
            den += e;
            acc0 = fmaf(e, bf_lo(w[j].x), acc0);
            acc1 = fmaf(e, bf_hi(w[j].x), acc1);
            acc2 = fmaf(e, bf_lo(w[j].y), acc2);
            acc3 = fmaf(e, bf_hi(w[j].y), acc3);
        }
    }
    for (; i < end; ++i) {
        const int s = esrc[i];
        float av = asrc[s * 4 + head] + ad;
        av = av > 0.f ? av : 0.2f * av;
        const float ex = __expf(av);
        const uint2 w = *(const uint2*)&h1b[(size_t)s * 128 + cb];
        den += ex;
        acc0 = fmaf(ex, bf_lo(w.x), acc0);
        acc1 = fmaf(ex, bf_hi(w.x), acc1);
        acc2 = fmaf(ex, bf_lo(w.y), acc2);
        acc3 = fmaf(ex, bf_hi(w.y), acc3);
    }

    const float inv = 1.f / (den + 1e-16f);
    const float4 bv = *(const float4*)&b[cb];
    float o0 = acc0 * inv + bv.x;
    float o1 = acc1 * inv + bv.y;
    float o2 = acc2 * inv + bv.z;
    float o3 = acc3 * inv + bv.w;
    o0 = o0 > 0.f ? o0 : expm1f(o0);
    o1 = o1 > 0.f ? o1 : expm1f(o1);
    o2 = o2 > 0.f ? o2 : expm1f(o2);
    o3 = o3 > 0.f ? o3 : expm1f(o3);
    uint2 o;
    o.x = pk_bf(o0, o1);
    o.y = pk_bf(o2, o3);
    *(uint2*)&agg1b[(size_t)node * 128 + cb] = o;
}

// ===========================================================================
// GEMM2 (MFMA): h2 = agg1 @ W2  [40000x128 @ 128x32], bf16 in, f32 accum.
// ===========================================================================
__global__ __launch_bounds__(256) void gemm2_kernel(
    const ushort* __restrict__ agg1b, const ushort* __restrict__ Wf2,
    const float* __restrict__ a_src, const float* __restrict__ a_dst,
    ushort* __restrict__ h2b, float* __restrict__ asrc, float* __restrict__ adst)
{
    const int wv = threadIdx.x >> 6;
    const int lane = threadIdx.x & 63;
    const int rowbase = blockIdx.x * 64 + wv * 16;
    const int arow = rowbase + (lane & 15);
    const int kof = (lane >> 4) * 8;

    f32x4 acc0 = {0.f,0.f,0.f,0.f}, acc1 = {0.f,0.f,0.f,0.f};
    const short8v* Wf2V = (const short8v*)Wf2;
#pragma unroll
    for (int kk = 0; kk < 4; ++kk) {
        const short8v af = *(const short8v*)&agg1b[(size_t)arow * 128 + kk * 32 + kof];
        const int base = kk * 2 * 64 + lane;
        acc0 = __builtin_amdgcn_mfma_f32_16x16x32_bf16(af, Wf2V[base], acc0, 0, 0, 0);
        acc1 = __builtin_amdgcn_mfma_f32_16x16x32_bf16(af, Wf2V[base + 64], acc1, 0, 0, 0);
    }

    const int cl = lane & 15;
    const int rg = lane >> 4;
    const float cs0 = a_src[cl], cs1 = a_src[16 + cl];
    const float cd0 = a_dst[cl], cd1 = a_dst[16 + cl];
#pragma unroll
    for (int r = 0; r < 4; ++r) {
        const int n = rowbase + rg * 4 + r;
        h2b[(size_t)n * 32 + cl]      = f2bf(acc0[r]);
        h2b[(size_t)n * 32 + 16 + cl] = f2bf(acc1[r]);
        float ps = acc0[r] * cs0 + acc1[r] * cs1;
        float pd = acc0[r] * cd0 + acc1[r] * cd1;
        ps += __shfl_xor(ps, 1); ps += __shfl_xor(ps, 2);
        ps += __shfl_xor(ps, 4); ps += __shfl_xor(ps, 8);
        pd += __shfl_xor(pd, 1); pd += __shfl_xor(pd, 2);
        pd += __shfl_xor(pd, 4); pd += __shfl_xor(pd, 8);
        if (cl == 0) { asrc[n] = ps; adst[n] = pd; }
    }
}

// ===========================================================================
// Gather pass 2: 32 lanes per dst node, bf16 h2 rows; 8-deep + 4-deep tail;
// ushort esrc; fused norm + bias + ELU; agg2 stored bf16.
// ===========================================================================
__global__ __launch_bounds__(256) void gather2_kernel(
    const int* __restrict__ rowptr, const int* __restrict__ bsum,
    const ushort* __restrict__ esrc,
    const float* __restrict__ asrc, const float* __restrict__ adst,
    const ushort* __restrict__ h2b, const float* __restrict__ b,
    ushort* __restrict__ agg2b)
{
    const int t = blockIdx.x * 256 + threadIdx.x;
    const int node = t >> 5;
    const int c = t & 31;
    if (node >= N_NODES) return;
    const float ad = adst[node];
    const int beg = rowptr[node] + bsum[node >> 8];
    const int end = rowptr[node + 1] + bsum[(node + 1) >> 8];
    float acc = 0.f, den = 0.f;

    int i = beg;
    for (; i + 8 <= end; i += 8) {
        int s[8];
        float a[8];
        ushort w[8];
#pragma unroll
        for (int j = 0; j < 8; ++j) s[j] = esrc[i + j];
#pragma unroll
        for (int j = 0; j < 8; ++j) a[j] = asrc[s[j]];
#pragma unroll
        for (int j = 0; j < 8; ++j) w[j] = h2b[(size_t)s[j] * 32 + c];
#pragma unroll
        for (int j = 0; j < 8; ++j) {
            float v = a[j] + ad; v = v > 0.f ? v : 0.2f * v;
            const float e = __expf(v);
            den += e;
            acc = fmaf(e, bf2f(w[j]), acc);
        }
    }
    for (; i + 4 <= end; i += 4) {   // 4-deep mid-tail
        int s[4];
        float a[4];
        ushort w[4];
#pragma unroll
        for (int j = 0; j < 4; ++j) s[j] = esrc[i + j];
#pragma unroll
        for (int j = 0; j < 4; ++j) a[j] = asrc[s[j]];
#pragma unroll
        for (int j = 0; j < 4; ++j) w[j] = h2b[(size_t)s[j] * 32 + c];
#pragma unroll
        for (int j = 0; j < 4; ++j) {
            float v = a[j] + ad; v = v > 0.f ? v : 0.2f * v;
            const float e = __expf(v);
            den += e;
            acc = fmaf(e, bf2f(w[j]), acc);
        }
    }
    for (; i < end; ++i) {
        const int s = esrc[i];
        float av = asrc[s] + ad;
        av = av > 0.f ? av : 0.2f * av;
        const float ex = __expf(av);
        den += ex;
        acc = fmaf(ex, bf2f(h2b[(size_t)s * 32 + c]), acc);
    }

    const float inv = 1.f / (den + 1e-16f);
    float o = acc * inv + b[c];
    o = o > 0.f ? o : expm1f(o);
    agg2b[(size_t)node * 32 + c] = f2bf(o);
}

// ===========================================================================
// Output GEMM (MFMA): out = agg2 @ W_out + b_out  [40000x32 @ 32x112].
// ===========================================================================
__global__ __launch_bounds__(256) void out_gemm_kernel(
    const ushort* __restrict__ agg2b, const ushort* __restrict__ Wfo,
    const float* __restrict__ b_out, float* __restrict__ out)
{
    const int wv = threadIdx.x >> 6;
    const int lane = threadIdx.x & 63;
    const int rowbase = blockIdx.x * 64 + wv * 16;
    const int arow = rowbase + (lane & 15);
    const int kof = (lane >> 4) * 8;

    const short8v af = *(const short8v*)&agg2b[(size_t)arow * 32 + kof];
    const short8v* WfoV = (const short8v*)Wfo;
    f32x4 acc[7];
#pragma unroll
    for (int ct = 0; ct < 7; ++ct) {
        f32x4 z = {0.f, 0.f, 0.f, 0.f};
        acc[ct] = __builtin_amdgcn_mfma_f32_16x16x32_bf16(af, WfoV[ct * 64 + lane], z, 0, 0, 0);
    }

    const int cl = lane & 15;
    const int rg = lane >> 4;
    float bo[7];
#pragma unroll
    for (int ct = 0; ct < 7; ++ct) bo[ct] = b_out[ct * 16 + cl];
#pragma unroll
    for (int r = 0; r < 4; ++r) {
        const int n = rowbase + rg * 4 + r;
        float* orow = &out[(size_t)n * 112 + cl];
#pragma unroll
        for (int ct = 0; ct < 7; ++ct) orow[ct * 16] = acc[ct][r] + bo[ct];
    }
}

// ===========================================================================
extern "C" void kernel_launch(void* const* d_in, const int* in_sizes, int n_in,
                              void* d_out, int out_size, void* d_ws, size_t ws_size,
                              hipStream_t stream) {
    const float* x      = (const float*)d_in[0];
    const int*   eidx   = (const int*)d_in[1];
    const float* W1     = (const float*)d_in[2];
    const float* a_src1 = (const float*)d_in[3];
    const float* a_dst1 = (const float*)d_in[4];
    const float* b1     = (const float*)d_in[5];
    const float* W2     = (const float*)d_in[6];
    const float* a_src2 = (const float*)d_in[7];
    const float* a_dst2 = (const float*)d_in[8];
    const float* b2     = (const float*)d_in[9];
    const float* W_out  = (const float*)d_in[10];
    const float* b_out  = (const float*)d_in[11];
    float* out = (float*)d_out;

    // ---- workspace layout (~26 MB) ----
    int* rowptr = (int*)d_ws;                 // 40064 (uses [0..40000])
    int* cnt    = rowptr + 40064;             // 40064 histogram (init = 1)
    int* bsum   = cnt + 40064;                // 192 block sums (exclusive)
    ushort* rank = (ushort*)(bsum + 192);     // 680000 (pad to 680064) per-edge rank
    ushort* Wf  = rank + 680064;              // 16384 bf16 (W1 fragments)
    ushort* Wf2 = Wf + 16384;                 // 4096 bf16 (W2 fragments)
    ushort* Wfo = Wf2 + 4096;                 // 3584 bf16 (+pad 512) W_out fragments
    ushort* esrc = Wfo + 4096;                // 680000 (pad 680064) CSR edge sources
    ushort* h1b  = esrc + 680064;             // 40000*128 bf16
    float* asrc1 = (float*)(h1b + 5120000);   // 40000*4
    float* adst1 = asrc1 + 160000;            // 40000*4
    ushort* agg1b = (ushort*)(adst1 + 160000); // 40000*128 bf16
    // after gather1, h1b region is dead -> layer-2 buffers overlay it
    ushort* h2b  = h1b;                       // 40000*32 bf16
    float* asrc2 = (float*)(h2b + 1280000);   // 40000
    float* adst2 = asrc2 + 40000;             // 40000
    ushort* agg2b = (ushort*)(adst2 + 40000); // 40000*32 bf16

    // cnt=1 init + W1/W2/W_out fragment packs
    prep_kernel<<<52, 256, 0, stream>>>(W1, W2, W_out, (int4*)cnt, Wf, Wf2, Wfo);

    // Layer-1 GEMM (MFMA) ∥ histogram-with-rank
    gemm1_hist_kernel<<<G1_BLOCKS + HIST_BLOCKS, 256, 0, stream>>>(
        x, Wf, a_src1, a_dst1, h1b, asrc1, adst1, eidx, cnt, rank);

    // CSR scan
    scanA_kernel<<<SCAN_BLOCKS, 256, 0, stream>>>(cnt, rowptr, bsum);
    scanB_kernel<<<1, 256, 0, stream>>>(bsum);

    // Atomic-free bucket fill (ushort)
    fill_kernel<<<(E_TOT + 255) / 256, 256, 0, stream>>>(
        eidx, rowptr, bsum, rank, esrc);

    // Layer 1 aggregate (bf16 out)
    gather1_kernel<<<5000, 256, 0, stream>>>(rowptr, bsum, esrc, asrc1, adst1,
                                             h1b, b1, agg1b);

    // Layer 2 (MFMA GEMM + gather)
    gemm2_kernel<<<625, 256, 0, stream>>>(agg1b, Wf2, a_src2, a_dst2,
                                          h2b, asrc2, adst2);
    gather2_kernel<<<5000, 256, 0, stream>>>(rowptr, bsum, esrc, asrc2, adst2,
                                             h2b, b2, agg2b);

    // Output projection (MFMA)
    out_gemm_kernel<<<625, 256, 0, stream>>>(agg2b, Wfo, b_out, out);
}